// Round 8
// baseline (310.997 us; speedup 1.0000x reference)
//
#include <hip/hip_runtime.h>

#define S 4096
#define DM 1024
#define NH 16
#define HD 64

typedef __attribute__((ext_vector_type(8))) short bf8;
typedef __attribute__((ext_vector_type(4))) float f4;
typedef __attribute__((ext_vector_type(4))) short s4;
typedef __attribute__((ext_vector_type(4))) unsigned int u4;

#define MFMA __builtin_amdgcn_mfma_f32_16x16x32_bf16

// softmax scale folded into Q, in base-2 domain: 1/sqrt(64) * log2(e)
#define QSCALE 0.18033688011112042f

static __device__ __forceinline__ unsigned short f2b(float f) {
  unsigned int u = __builtin_bit_cast(unsigned int, f);
  u += 0x7fffu + ((u >> 16) & 1u);   // RNE
  return (unsigned short)(u >> 16);
}
static __device__ __forceinline__ float b2f(unsigned short u) {
  return __builtin_bit_cast(float, (unsigned int)u << 16);
}

// async global->LDS, 16B per lane. LDS dest must be WAVE-UNIFORM base;
// HW scatters lane i to base + i*16.
static __device__ __forceinline__ void gld_lds(const unsigned short* g, unsigned short* l) {
  __builtin_amdgcn_global_load_lds(
      (const __attribute__((address_space(1))) unsigned int*)g,
      (__attribute__((address_space(3))) unsigned int*)l, 16, 0, 0);
}

// ------------- fused prep: cast x->bf16 ; transpose+cast w_qkv, w_out -------------
// blocks 0..4095: cast x (4M elems). 4096..4863: wqkvT tiles. 4864..5119: woutT tiles.
__global__ void prep(const float* __restrict__ x, const float* __restrict__ w_qkv,
                     const float* __restrict__ w_out,
                     unsigned short* __restrict__ xb, unsigned short* __restrict__ wqkvT,
                     unsigned short* __restrict__ woutT) {
  __shared__ float tile[64][65];
  int b = blockIdx.x, t = threadIdx.x;
  if (b < 4096) {
    int i = (b * 256 + t) * 4;
    float4 v = *(const float4*)(x + i);
    s4 o;
    o.x = (short)f2b(v.x); o.y = (short)f2b(v.y);
    o.z = (short)f2b(v.z); o.w = (short)f2b(v.w);
    *(s4*)(xb + i) = o;
    return;
  }
  const float* in; unsigned short* out; int R, C, tc, tr;
  if (b < 4096 + 768) { int bb = b - 4096; in = w_qkv; out = wqkvT; R = DM; C = 3 * DM; tc = bb % 48; tr = bb / 48; }
  else                { int bb = b - 4864; in = w_out; out = woutT; R = DM; C = DM;     tc = bb % 16; tr = bb / 16; }
  int c = t & 63, rbase = (t >> 6) * 16;
#pragma unroll
  for (int i = 0; i < 16; i++) {
    int r = rbase + i;
    tile[r][c] = in[(tr * 64 + r) * C + tc * 64 + c];
  }
  __syncthreads();
#pragma unroll
  for (int i = 0; i < 16; i++) {
    int cc = rbase + i;
    out[(tc * 64 + cc) * R + tr * 64 + c] = f2b(tile[c][cc]);
  }
}

// =================================================================
// GEMM cores (R6 BK=64 form — unchanged this round).
// =================================================================

// ------------- QKV GEMM + scatter epilogue (128x128, BK=64, 4 waves) -------------
__global__ void __launch_bounds__(256, 2) gemm_qkv(const unsigned short* __restrict__ A,
                                                   const unsigned short* __restrict__ Bt,
                                                   const float* __restrict__ bias,
                                                   unsigned short* __restrict__ Qo,
                                                   unsigned short* __restrict__ Ko,
                                                   unsigned short* __restrict__ Vt) {
  __shared__ unsigned short lA[128 * 64];   // 16 KB, [row][64] swizzled chunks
  __shared__ unsigned short lB[128 * 64];   // 16 KB
  int bid = blockIdx.x;
  int nb = bid % 24, mb = bid / 24;
  int m0 = mb * 128, n0 = nb * 128;
  int t = threadIdx.x, w = t >> 6, lane = t & 63;
  int col = lane & 15, quad = lane >> 4;
  int wm = (w >> 1) * 64, wn = (w & 1) * 64;

  int srow = lane >> 3;          // 0..7 within an 8-row staging group
  int sphys = lane & 7;

  f4 acc[4][4];
#pragma unroll
  for (int x = 0; x < 4; x++)
#pragma unroll
    for (int y = 0; y < 4; y++) acc[x][y] = (f4){0.f, 0.f, 0.f, 0.f};

  for (int k0 = 0; k0 < DM; k0 += 64) {
    __syncthreads();   // WAR: prev-step consumers done
#pragma unroll
    for (int p = 0; p < 4; p++) {
      int j = 4 * w + p;                       // 16 groups of 8 rows
      int row = j * 8 + srow;                  // 0..127
      int lch = sphys ^ (row & 7);             // logical 16B chunk to fetch
      gld_lds(A + (size_t)(m0 + row) * DM + k0 + lch * 8, lA + j * 512);
      gld_lds(Bt + (size_t)(n0 + row) * DM + k0 + lch * 8, lB + j * 512);
    }
    __syncthreads();   // staged data visible

#pragma unroll
    for (int ks = 0; ks < 2; ks++) {
      bf8 af[4], bfr[4];
      int sw = col & 7;
#pragma unroll
      for (int x = 0; x < 4; x++) {
        int rA = wm + x * 16 + col;
        af[x] = *(const bf8*)(lA + rA * 64 + ((quad + 4 * ks) ^ sw) * 8);
        int rB = wn + x * 16 + col;
        bfr[x] = *(const bf8*)(lB + rB * 64 + ((quad + 4 * ks) ^ sw) * 8);
      }
#pragma unroll
      for (int x = 0; x < 4; x++)
#pragma unroll
        for (int y = 0; y < 4; y++)
          acc[x][y] = MFMA(af[x], bfr[y], acc[x][y], 0, 0, 0);
    }
  }

  // epilogue: scatter to Q (scaled), K, Vt
#pragma unroll
  for (int x = 0; x < 4; x++) {
    int s0r = m0 + wm + x * 16 + quad * 4;
#pragma unroll
    for (int y = 0; y < 4; y++) {
      f4 a = acc[x][y];
      int n = n0 + wn + y * 16 + col;
      float bv = bias[n];
      if (n < 2048) {
        unsigned short* dst = (n < 1024) ? Qo : Ko;
        float sc = (n < 1024) ? QSCALE : 1.0f;
        int nn = n & 1023;
        int hh = nn >> 6, d = nn & 63;
        unsigned short* pp = dst + ((size_t)hh * S + s0r) * HD + d;
#pragma unroll
        for (int r = 0; r < 4; r++) pp[r * HD] = f2b((a[r] + bv) * sc);
      } else {
        int nn = n - 2048;
        int hh = nn >> 6, d = nn & 63;
        s4 pk;
        pk.x = (short)f2b(a[0] + bv);
        pk.y = (short)f2b(a[1] + bv);
        pk.z = (short)f2b(a[2] + bv);
        pk.w = (short)f2b(a[3] + bv);
        *(s4*)(Vt + ((size_t)hh * HD + d) * S + s0r) = pk;
      }
    }
  }
}

// ------------- Out GEMM: ctx x woutT + bias -> fp32 (64x128, BK=64) -------------
__global__ void __launch_bounds__(256, 2) gemm_out(const unsigned short* __restrict__ A,
                                                   const unsigned short* __restrict__ Bt,
                                                   const float* __restrict__ bias,
                                                   float* __restrict__ out) {
  __shared__ unsigned short lA[64 * 64];    //  8 KB
  __shared__ unsigned short lB[128 * 64];   // 16 KB
  int bid = blockIdx.x;
  int nb = bid % 8, mb = bid / 8;              // mb 0..63; nb==bid%8 -> per-XCD B-panel affinity
  int m0 = mb * 64, n0 = nb * 128;
  int t = threadIdx.x, w = t >> 6, lane = t & 63;
  int col = lane & 15, quad = lane >> 4;
  int wm = (w >> 1) * 32, wn = (w & 1) * 64;

  int srow = lane >> 3;
  int sphys = lane & 7;

  f4 acc[2][4];
#pragma unroll
  for (int x = 0; x < 2; x++)
#pragma unroll
    for (int y = 0; y < 4; y++) acc[x][y] = (f4){0.f, 0.f, 0.f, 0.f};

  for (int k0 = 0; k0 < DM; k0 += 64) {
    __syncthreads();
#pragma unroll
    for (int p = 0; p < 2; p++) {
      int j = 2 * w + p;                       // A: 8 groups of 8 rows
      int row = j * 8 + srow;                  // 0..63
      int lch = sphys ^ (row & 7);
      gld_lds(A + (size_t)(m0 + row) * DM + k0 + lch * 8, lA + j * 512);
    }
#pragma unroll
    for (int p = 0; p < 4; p++) {
      int j = 4 * w + p;                       // B: 16 groups of 8 rows
      int row = j * 8 + srow;                  // 0..127
      int lch = sphys ^ (row & 7);
      gld_lds(Bt + (size_t)(n0 + row) * DM + k0 + lch * 8, lB + j * 512);
    }
    __syncthreads();

#pragma unroll
    for (int ks = 0; ks < 2; ks++) {
      bf8 af[2], bfr[4];
      int sw = col & 7;
#pragma unroll
      for (int x = 0; x < 2; x++) {
        int rA = wm + x * 16 + col;
        af[x] = *(const bf8*)(lA + rA * 64 + ((quad + 4 * ks) ^ sw) * 8);
      }
#pragma unroll
      for (int y = 0; y < 4; y++) {
        int rB = wn + y * 16 + col;
        bfr[y] = *(const bf8*)(lB + rB * 64 + ((quad + 4 * ks) ^ sw) * 8);
      }
#pragma unroll
      for (int x = 0; x < 2; x++)
#pragma unroll
        for (int y = 0; y < 4; y++)
          acc[x][y] = MFMA(af[x], bfr[y], acc[x][y], 0, 0, 0);
    }
  }

#pragma unroll
  for (int x = 0; x < 2; x++) {
    int s0r = m0 + wm + x * 16 + quad * 4;
#pragma unroll
    for (int y = 0; y < 4; y++) {
      f4 a = acc[x][y];
      int n = n0 + wn + y * 16 + col;
      float bv = bias[n];
#pragma unroll
      for (int r = 0; r < 4; r++) out[(size_t)(s0r + r) * DM + n] = a[r] + bv;
    }
  }
}

// =================================================================
// Split-KV flash attention, fixed-max (m=0) softmax.
// R8: BARRIER-FREE. K/V are L2-resident (R7 head->XCD affinity,
// FETCH 84->12MB proved it), so LDS staging no longer buys coalescing
// — it only costs 2 barriers + a vmcnt drain per step. Delete LDS
// entirely; load K/V MFMA fragments directly from global (L2):
//   ka = K[(kv0+tt*16+col)*HD + quad*8]      (16B/lane)
//   kb = ... + 32
//   v0 = Vt[(dt*16+col)*S + kv0 + quad*8]
//   v1 = ... + 32
// (derived from the kbuf/vbuf swizzle identities; XOR cancels.)
// Waves are fully independent: no __syncthreads anywhere. V loads
// issue right after QK^T so softmax covers their L2 latency.
// Schedule: 16 heads x 160 chunks (1/2/4-way split) with head->XCD
// affinity, unchanged from R7.
// =================================================================
__global__ void __launch_bounds__(128, 4) attn(const unsigned short* __restrict__ Q,
                                               const unsigned short* __restrict__ K,
                                               const unsigned short* __restrict__ Vt,
                                               unsigned short* __restrict__ slabA,
                                               unsigned short* __restrict__ slab1,
                                               unsigned short* __restrict__ slab2,
                                               unsigned short* __restrict__ slab3,
                                               float* __restrict__ l0_g,
                                               float* __restrict__ l1_g,
                                               float* __restrict__ l2_g,
                                               float* __restrict__ l3_g) {
  int bid = blockIdx.x;
  int xcd = bid & 7;                             // dispatch round-robin heuristic
  int kk = bid >> 3;                             // 0..319 within this XCD
  int h = xcd + ((kk >= 160) ? 8 : 0);           // heads h, h+8 pinned to XCD h
  int cidx = (kk >= 160) ? (kk - 160) : kk;      // 0..159
  int j = 159 - cidx;                            // longest chunks first
  int qb, c0, nst, p;
  if (j < 16) {
    qb = j; c0 = 0; nst = qb + 1; p = 0;
  } else if (j < 64) {
    int u = j - 16;
    qb = 16 + (u >> 1);
    int half = u & 1;
    int ntot = qb + 1, nh = (ntot + 1) >> 1;
    p = half;
    if (half) { c0 = nh; nst = ntot - nh; }
    else      { c0 = 0;  nst = nh; }
  } else {
    int u = j - 64;
    qb = 40 + (u >> 2);
    int qt = u & 3;
    int ntot = qb + 1;
    int base = ntot >> 2, rem = ntot & 3;
    c0 = qt * base + (qt < rem ? qt : rem);
    nst = base + (qt < rem ? 1 : 0);
    p = qt;
  }
  bool single = (qb < 16);
  int q0blk = qb * 64;
  int t = threadIdx.x, w = t >> 6, lane = t & 63;
  int col = lane & 15, quad = lane >> 4;
  int q0 = q0blk + w * 32;                       // wave covers 32 q-rows

  const unsigned short* Qh = Q + (size_t)h * S * HD;
  const unsigned short* Kh = K + (size_t)h * S * HD;
  const unsigned short* Vh = Vt + (size_t)h * HD * S;

  // Q^T B-fragments for the 2 q-groups: lane holds Q[q16+col][k-range]
  bf8 qf[2][2];
#pragma unroll
  for (int g = 0; g < 2; g++) {
    qf[g][0] = *(const bf8*)(Qh + (q0 + g * 16 + col) * HD + quad * 8);
    qf[g][1] = *(const bf8*)(Qh + (q0 + g * 16 + col) * HD + 32 + quad * 8);
  }

  f4 o[2][4];
#pragma unroll
  for (int g = 0; g < 2; g++)
#pragma unroll
    for (int dt = 0; dt < 4; dt++) o[g][dt] = (f4){0.f, 0.f, 0.f, 0.f};
  float lsum[2] = {0.f, 0.f};                    // per-lane partial; reduced at end

  for (int s_ = 0; s_ < nst; s_++) {
    int kv0 = (c0 + s_) * 64;

    // ---- K fragments direct from L2 ----
    bf8 ka[4], kb[4];
#pragma unroll
    for (int tt = 0; tt < 4; tt++) {
      const unsigned short* kp = Kh + (size_t)(kv0 + tt * 16 + col) * HD;
      ka[tt] = *(const bf8*)(kp + quad * 8);
      kb[tt] = *(const bf8*)(kp + 32 + quad * 8);
    }

    // ---- scores S^T[kv][q]; K-frags shared by both q-groups ----
    f4 st[2][4];
#pragma unroll
    for (int tt = 0; tt < 4; tt++) {
#pragma unroll
      for (int g = 0; g < 2; g++) {
        f4 z = {0.f, 0.f, 0.f, 0.f};
        z = MFMA(ka[tt], qf[g][0], z, 0, 0, 0);
        z = MFMA(kb[tt], qf[g][1], z, 0, 0, 0);
        st[g][tt] = z;
      }
    }

    // ---- V fragments: issue now; softmax below covers their latency ----
    bf8 v0[4], v1[4];
#pragma unroll
    for (int dt = 0; dt < 4; dt++) {
      const unsigned short* vp = Vh + (size_t)(dt * 16 + col) * S + kv0;
      v0[dt] = *(const bf8*)(vp + quad * 8);
      v1[dt] = *(const bf8*)(vp + 32 + quad * 8);
    }

#pragma unroll
    for (int g = 0; g < 2; g++) {
      int q16 = q0 + g * 16;
      if (kv0 + 63 > q16) {                    // diagonal / masked tiles
        int q = q16 + col;
#pragma unroll
        for (int tt = 0; tt < 4; tt++)
#pragma unroll
          for (int rr = 0; rr < 4; rr++) {
            int kv = kv0 + tt * 16 + quad * 4 + rr;
            st[g][tt][rr] = (kv <= q) ? st[g][tt][rr] : -1e30f;
          }
      }
    }

    // ---- fixed-max softmax + in-register P transpose ----
    // st layout: lane(quad,col) holds P[q=col][kv=16tt+4quad+rr].
    // PV A-fragment needs:     lane(quad,col) holds P[q=col][kv=8quad+j].
    // cvt_pk pairs -> permlane32_swap -> permlane16_swap.
    bf8 pf[2][2];
#pragma unroll
    for (int g = 0; g < 2; g++) {
      float pv[4][4];
#pragma unroll
      for (int tt = 0; tt < 4; tt++) {
#pragma unroll
        for (int rr = 0; rr < 4; rr++) pv[tt][rr] = __builtin_amdgcn_exp2f(st[g][tt][rr]);
        lsum[g] += (pv[tt][0] + pv[tt][1]) + (pv[tt][2] + pv[tt][3]);
      }
#pragma unroll
      for (int f = 0; f < 2; f++) {
        unsigned int a0, a1, b0, b1;
        asm("v_cvt_pk_bf16_f32 %0, %1, %2" : "=v"(a0) : "v"(pv[2 * f][0]),     "v"(pv[2 * f][1]));
        asm("v_cvt_pk_bf16_f32 %0, %1, %2" : "=v"(a1) : "v"(pv[2 * f][2]),     "v"(pv[2 * f][3]));
        asm("v_cvt_pk_bf16_f32 %0, %1, %2" : "=v"(b0) : "v"(pv[2 * f + 1][0]), "v"(pv[2 * f + 1][1]));
        asm("v_cvt_pk_bf16_f32 %0, %1, %2" : "=v"(b1) : "v"(pv[2 * f + 1][2]), "v"(pv[2 * f + 1][3]));
        asm("v_permlane32_swap_b32 %0, %1" : "+v"(a0), "+v"(b0));
        asm("v_permlane32_swap_b32 %0, %1" : "+v"(a1), "+v"(b1));
        asm("v_permlane16_swap_b32 %0, %1" : "+v"(a0), "+v"(b0));
        asm("v_permlane16_swap_b32 %0, %1" : "+v"(a1), "+v"(b1));
        u4 pk;
        pk.x = a0; pk.y = a1; pk.z = b0; pk.w = b1;
        pf[g][f] = __builtin_bit_cast(bf8, pk);
      }
    }

    // ---- PV: V-frags shared by both q-groups ----
#pragma unroll
    for (int dt = 0; dt < 4; dt++) {
#pragma unroll
      for (int g = 0; g < 2; g++) {
        o[g][dt] = MFMA(pf[g][0], v0[dt], o[g][dt], 0, 0, 0);
        o[g][dt] = MFMA(pf[g][1], v1[dt], o[g][dt], 0, 0, 0);
      }
    }
  }

  // ---- epilogue per q-group: cross-lane l reduce (q = col) ----
#pragma unroll
  for (int g = 0; g < 2; g++) {
    float ls = lsum[g];
    ls += __shfl_xor(ls, 16);
    ls += __shfl_xor(ls, 32);
    int q16 = q0 + g * 16;
    if (single) {
      float inv = 1.0f / ls;
      float ir[4];
#pragma unroll
      for (int rr = 0; rr < 4; rr++) ir[rr] = __shfl(inv, quad * 4 + rr);
#pragma unroll
      for (int dt = 0; dt < 4; dt++)
#pragma unroll
        for (int rr = 0; rr < 4; rr++) {
          int row = q16 + quad * 4 + rr;
          slabA[(size_t)row * DM + h * HD + dt * 16 + col] = f2b(o[g][dt][rr] * ir[rr]);
        }
    } else {
      unsigned short* slab; int rowbase; float* lg;
      if (p == 0)      { slab = slabA; rowbase = q16;        lg = l0_g; }
      else if (p == 1) { slab = slab1; rowbase = q16 - 1024; lg = l1_g; }
      else if (p == 2) { slab = slab2; rowbase = q16 - 2560; lg = l2_g; }
      else             { slab = slab3; rowbase = q16 - 2560; lg = l3_g; }
      if (quad == 0) lg[h * S + q16 + col] = ls;
#pragma unroll
      for (int dt = 0; dt < 4; dt++)
#pragma unroll
        for (int rr = 0; rr < 4; rr++) {
          int row = rowbase + quad * 4 + rr;
          slab[(size_t)row * DM + h * HD + dt * 16 + col] = f2b(o[g][dt][rr]);
        }
    }
  }
}

// ------------- combine bf16 partials -> normalized ctx rows 1024+ -------------
// rows 1024..2559: 2 partials (ctx + slab1); rows 2560..4095: 4 partials.
__global__ void combine(unsigned short* __restrict__ Ctx,
                        const unsigned short* __restrict__ slab1,
                        const unsigned short* __restrict__ slab2,
                        const unsigned short* __restrict__ slab3,
                        const float* __restrict__ l0_g,
                        const float* __restrict__ l1_g,
                        const float* __restrict__ l2_g,
                        const float* __restrict__ l3_g) {
  int row = 1024 + blockIdx.x;
  int cc = threadIdx.x * 4;
  int h = cc >> 6;
  s4 a = *(const s4*)(Ctx + (size_t)row * DM + cc);
  s4 b = *(const s4*)(slab1 + (size_t)(row - 1024) * DM + cc);
  float acc0 = b2f((unsigned short)a.x) + b2f((unsigned short)b.x);
  float acc1 = b2f((unsigned short)a.y) + b2f((unsigned short)b.y);
  float acc2 = b2f((unsigned short)a.z) + b2f((unsigned short)b.z);
  float acc3 = b2f((unsigned short)a.w) + b2f((unsigned short)b.w);
  float l = l0_g[h * S + row] + l1_g[h * S + row];
  if (row >= 2560) {
    s4 c = *(const s4*)(slab2 + (size_t)(row - 2560) * DM + cc);
    s4 d = *(const s4*)(slab3 + (size_t)(row - 2560) * DM + cc);
    acc0 += b2f((unsigned short)c.x) + b2f((unsigned short)d.x);
    acc1 += b2f((unsigned short)c.y) + b2f((unsigned short)d.y);
    acc2 += b2f((unsigned short)c.z) + b2f((unsigned short)d.z);
    acc3 += b2f((unsigned short)c.w) + b2f((unsigned short)d.w);
    l += l2_g[h * S + row] + l3_g[h * S + row];
  }
  float inv = 1.0f / l;
  s4 o;
  o.x = (short)f2b(acc0 * inv);
  o.y = (short)f2b(acc1 * inv);
  o.z = (short)f2b(acc2 * inv);
  o.w = (short)f2b(acc3 * inv);
  *(s4*)(Ctx + (size_t)row * DM + cc) = o;
}

extern "C" void kernel_launch(void* const* d_in, const int* in_sizes, int n_in,
                              void* d_out, int out_size, void* d_ws, size_t ws_size,
                              hipStream_t stream) {
  const float* x     = (const float*)d_in[0];
  const float* w_qkv = (const float*)d_in[1];
  const float* b_qkv = (const float*)d_in[2];
  const float* w_out = (const float*)d_in[3];
  const float* b_out = (const float*)d_in[4];
  float* out = (float*)d_out;

  char* ws = (char*)d_ws;
  unsigned short* xb    = (unsigned short*)(ws);                        //  8 MB (dead after gemm_qkv)
  unsigned short* wqkvT = (unsigned short*)(ws + (size_t)8  * 1048576); //  6 MB (dead after gemm_qkv)
  unsigned short* woutT = (unsigned short*)(ws + (size_t)14 * 1048576); //  2 MB (live till gemm_out)
  unsigned short* Qb    = (unsigned short*)(ws + (size_t)16 * 1048576); //  8 MB
  unsigned short* Kb    = (unsigned short*)(ws + (size_t)24 * 1048576); //  8 MB
  unsigned short* Vtb   = (unsigned short*)(ws + (size_t)32 * 1048576); //  8 MB
  unsigned short* ctx   = (unsigned short*)(ws + (size_t)40 * 1048576); //  8 MB (= slabA)

  // dead-region reuse (gemm_qkv has consumed xb/wqkvT before attn runs):
  // xb region (8MB):    slab1 (rows 1024+, 6MB) + l0..l3 (4 x 256KB)
  // wqkvT region (6MB): slab2 (rows 2560+, 3MB) + slab3 (3MB)
  unsigned short* slab1 = xb;
  float* l0_g = (float*)(ws + (size_t)6 * 1048576);
  float* l1_g = (float*)(ws + (size_t)6 * 1048576 + 256 * 1024);
  float* l2_g = (float*)(ws + (size_t)6 * 1048576 + 512 * 1024);
  float* l3_g = (float*)(ws + (size_t)6 * 1048576 + 768 * 1024);
  unsigned short* slab2 = wqkvT;
  unsigned short* slab3 = (unsigned short*)(ws + (size_t)11 * 1048576);

  prep<<<5120, 256, 0, stream>>>(x, w_qkv, w_out, xb, wqkvT, woutT);
  gemm_qkv<<<32 * 24, 256, 0, stream>>>(xb, wqkvT, b_qkv, Qb, Kb, Vtb);
  attn<<<NH * 160, 128, 0, stream>>>(Qb, Kb, Vtb, ctx, slab1, slab2, slab3,
                                     l0_g, l1_g, l2_g, l3_g);
  combine<<<3072, 256, 0, stream>>>(ctx, slab1, slab2, slab3, l0_g, l1_g, l2_g, l3_g);
  gemm_out<<<64 * 8, 256, 0, stream>>>(ctx, woutT, b_out, out);
}

// Round 9
// 196.059 us; speedup vs baseline: 1.5862x; 1.5862x over previous
//
#include <hip/hip_runtime.h>

#define S 4096
#define DM 1024
#define NH 16
#define HD 64

typedef __attribute__((ext_vector_type(8))) short bf8;
typedef __attribute__((ext_vector_type(4))) float f4;
typedef __attribute__((ext_vector_type(4))) short s4;
typedef __attribute__((ext_vector_type(4))) unsigned int u4;

#define MFMA __builtin_amdgcn_mfma_f32_16x16x32_bf16

// softmax scale folded into Q, in base-2 domain: 1/sqrt(64) * log2(e)
#define QSCALE 0.18033688011112042f

static __device__ __forceinline__ unsigned short f2b(float f) {
  unsigned int u = __builtin_bit_cast(unsigned int, f);
  u += 0x7fffu + ((u >> 16) & 1u);   // RNE
  return (unsigned short)(u >> 16);
}
static __device__ __forceinline__ float b2f(unsigned short u) {
  return __builtin_bit_cast(float, (unsigned int)u << 16);
}

// async global->LDS, 16B per lane. LDS dest must be WAVE-UNIFORM base;
// HW scatters lane i to base + i*16.
static __device__ __forceinline__ void gld_lds(const unsigned short* g, unsigned short* l) {
  __builtin_amdgcn_global_load_lds(
      (const __attribute__((address_space(1))) unsigned int*)g,
      (__attribute__((address_space(3))) unsigned int*)l, 16, 0, 0);
}

// ------------- fused prep: cast x->bf16 ; transpose+cast w_qkv, w_out -------------
// blocks 0..4095: cast x (4M elems). 4096..4863: wqkvT tiles. 4864..5119: woutT tiles.
__global__ void prep(const float* __restrict__ x, const float* __restrict__ w_qkv,
                     const float* __restrict__ w_out,
                     unsigned short* __restrict__ xb, unsigned short* __restrict__ wqkvT,
                     unsigned short* __restrict__ woutT) {
  __shared__ float tile[64][65];
  int b = blockIdx.x, t = threadIdx.x;
  if (b < 4096) {
    int i = (b * 256 + t) * 4;
    float4 v = *(const float4*)(x + i);
    s4 o;
    o.x = (short)f2b(v.x); o.y = (short)f2b(v.y);
    o.z = (short)f2b(v.z); o.w = (short)f2b(v.w);
    *(s4*)(xb + i) = o;
    return;
  }
  const float* in; unsigned short* out; int R, C, tc, tr;
  if (b < 4096 + 768) { int bb = b - 4096; in = w_qkv; out = wqkvT; R = DM; C = 3 * DM; tc = bb % 48; tr = bb / 48; }
  else                { int bb = b - 4864; in = w_out; out = woutT; R = DM; C = DM;     tc = bb % 16; tr = bb / 16; }
  int c = t & 63, rbase = (t >> 6) * 16;
#pragma unroll
  for (int i = 0; i < 16; i++) {
    int r = rbase + i;
    tile[r][c] = in[(tr * 64 + r) * C + tc * 64 + c];
  }
  __syncthreads();
#pragma unroll
  for (int i = 0; i < 16; i++) {
    int cc = rbase + i;
    out[(tc * 64 + cc) * R + tr * 64 + c] = f2b(tile[c][cc]);
  }
}

// =================================================================
// GEMM cores, R9: smaller tiles -> higher block residency (the one
// lever with a verified win here: R4 attn 10 blk/CU). BK=64 kept.
// =================================================================

// ------------- QKV GEMM + scatter epilogue (64x128, BK=64, 4 waves, 6 blk/CU) -------------
__global__ void __launch_bounds__(256, 2) gemm_qkv(const unsigned short* __restrict__ A,
                                                   const unsigned short* __restrict__ Bt,
                                                   const float* __restrict__ bias,
                                                   unsigned short* __restrict__ Qo,
                                                   unsigned short* __restrict__ Ko,
                                                   unsigned short* __restrict__ Vt) {
  __shared__ unsigned short lA[64 * 64];    //  8 KB, [row][64] swizzled chunks
  __shared__ unsigned short lB[128 * 64];   // 16 KB
  int bid = blockIdx.x;
  int nb = bid % 24, mb = bid / 24;            // mb 0..63; bid%8 = nb%8 -> B-panel XCD affinity
  int m0 = mb * 64, n0 = nb * 128;
  int t = threadIdx.x, w = t >> 6, lane = t & 63;
  int col = lane & 15, quad = lane >> 4;
  int wm = (w >> 1) * 32, wn = (w & 1) * 64;   // wave covers 32x64

  int srow = lane >> 3;          // 0..7 within an 8-row staging group
  int sphys = lane & 7;

  f4 acc[2][4];
#pragma unroll
  for (int x = 0; x < 2; x++)
#pragma unroll
    for (int y = 0; y < 4; y++) acc[x][y] = (f4){0.f, 0.f, 0.f, 0.f};

  for (int k0 = 0; k0 < DM; k0 += 64) {
    __syncthreads();   // WAR: prev-step consumers done
#pragma unroll
    for (int p = 0; p < 2; p++) {
      int j = 2 * w + p;                       // A: 8 groups of 8 rows (64)
      int row = j * 8 + srow;
      int lch = sphys ^ (row & 7);
      gld_lds(A + (size_t)(m0 + row) * DM + k0 + lch * 8, lA + j * 512);
    }
#pragma unroll
    for (int p = 0; p < 4; p++) {
      int j = 4 * w + p;                       // B: 16 groups of 8 rows (128)
      int row = j * 8 + srow;
      int lch = sphys ^ (row & 7);
      gld_lds(Bt + (size_t)(n0 + row) * DM + k0 + lch * 8, lB + j * 512);
    }
    __syncthreads();   // staged data visible

#pragma unroll
    for (int ks = 0; ks < 2; ks++) {
      bf8 af[2], bfr[4];
      int sw = col & 7;
#pragma unroll
      for (int x = 0; x < 2; x++) {
        int rA = wm + x * 16 + col;
        af[x] = *(const bf8*)(lA + rA * 64 + ((quad + 4 * ks) ^ sw) * 8);
      }
#pragma unroll
      for (int y = 0; y < 4; y++) {
        int rB = wn + y * 16 + col;
        bfr[y] = *(const bf8*)(lB + rB * 64 + ((quad + 4 * ks) ^ sw) * 8);
      }
#pragma unroll
      for (int x = 0; x < 2; x++)
#pragma unroll
        for (int y = 0; y < 4; y++)
          acc[x][y] = MFMA(af[x], bfr[y], acc[x][y], 0, 0, 0);
    }
  }

  // epilogue: scatter to Q (scaled), K, Vt
#pragma unroll
  for (int x = 0; x < 2; x++) {
    int s0r = m0 + wm + x * 16 + quad * 4;
#pragma unroll
    for (int y = 0; y < 4; y++) {
      f4 a = acc[x][y];
      int n = n0 + wn + y * 16 + col;
      float bv = bias[n];
      if (n < 2048) {
        unsigned short* dst = (n < 1024) ? Qo : Ko;
        float sc = (n < 1024) ? QSCALE : 1.0f;
        int nn = n & 1023;
        int hh = nn >> 6, d = nn & 63;
        unsigned short* pp = dst + ((size_t)hh * S + s0r) * HD + d;
#pragma unroll
        for (int r = 0; r < 4; r++) pp[r * HD] = f2b((a[r] + bv) * sc);
      } else {
        int nn = n - 2048;
        int hh = nn >> 6, d = nn & 63;
        s4 pk;
        pk.x = (short)f2b(a[0] + bv);
        pk.y = (short)f2b(a[1] + bv);
        pk.z = (short)f2b(a[2] + bv);
        pk.w = (short)f2b(a[3] + bv);
        *(s4*)(Vt + ((size_t)hh * HD + d) * S + s0r) = pk;
      }
    }
  }
}

// ------------- Out GEMM: ctx x woutT + bias -> fp32 (64x64, BK=64, 4 blk/CU) -------------
__global__ void __launch_bounds__(256, 2) gemm_out(const unsigned short* __restrict__ A,
                                                   const unsigned short* __restrict__ Bt,
                                                   const float* __restrict__ bias,
                                                   float* __restrict__ out) {
  __shared__ unsigned short lA[64 * 64];    //  8 KB
  __shared__ unsigned short lB[64 * 64];    //  8 KB
  int bid = blockIdx.x;
  int nb = bid % 16, mb = bid / 16;            // mb 0..63, nb 0..15
  int m0 = mb * 64, n0 = nb * 64;
  int t = threadIdx.x, w = t >> 6, lane = t & 63;
  int col = lane & 15, quad = lane >> 4;
  int wm = (w >> 1) * 32, wn = (w & 1) * 32;   // wave covers 32x32

  int srow = lane >> 3;
  int sphys = lane & 7;

  f4 acc[2][2];
#pragma unroll
  for (int x = 0; x < 2; x++)
#pragma unroll
    for (int y = 0; y < 2; y++) acc[x][y] = (f4){0.f, 0.f, 0.f, 0.f};

  for (int k0 = 0; k0 < DM; k0 += 64) {
    __syncthreads();
#pragma unroll
    for (int p = 0; p < 2; p++) {
      int j = 2 * w + p;                       // A: 8 groups of 8 rows
      int row = j * 8 + srow;
      int lch = sphys ^ (row & 7);
      gld_lds(A + (size_t)(m0 + row) * DM + k0 + lch * 8, lA + j * 512);
    }
#pragma unroll
    for (int p = 0; p < 2; p++) {
      int j = 2 * w + p;                       // B: 8 groups of 8 rows
      int row = j * 8 + srow;
      int lch = sphys ^ (row & 7);
      gld_lds(Bt + (size_t)(n0 + row) * DM + k0 + lch * 8, lB + j * 512);
    }
    __syncthreads();

#pragma unroll
    for (int ks = 0; ks < 2; ks++) {
      bf8 af[2], bfr[2];
      int sw = col & 7;
#pragma unroll
      for (int x = 0; x < 2; x++) {
        int rA = wm + x * 16 + col;
        af[x] = *(const bf8*)(lA + rA * 64 + ((quad + 4 * ks) ^ sw) * 8);
      }
#pragma unroll
      for (int y = 0; y < 2; y++) {
        int rB = wn + y * 16 + col;
        bfr[y] = *(const bf8*)(lB + rB * 64 + ((quad + 4 * ks) ^ sw) * 8);
      }
#pragma unroll
      for (int x = 0; x < 2; x++)
#pragma unroll
        for (int y = 0; y < 2; y++)
          acc[x][y] = MFMA(af[x], bfr[y], acc[x][y], 0, 0, 0);
    }
  }

#pragma unroll
  for (int x = 0; x < 2; x++) {
    int s0r = m0 + wm + x * 16 + quad * 4;
#pragma unroll
    for (int y = 0; y < 2; y++) {
      f4 a = acc[x][y];
      int n = n0 + wn + y * 16 + col;
      float bv = bias[n];
#pragma unroll
      for (int r = 0; r < 4; r++) out[(size_t)(s0r + r) * DM + n] = a[r] + bv;
    }
  }
}

// =================================================================
// Split-KV flash attention, fixed-max (m=0) softmax — EXACT R7 body
// (proven 64us): single-buffer 16KB LDS, 2 barriers/step,
// global_load_lds staging, head->XCD affinity (FETCH 12MB, L2-resident
// K/V), 16 heads x 160 chunks (1/2/4-way split).
// =================================================================
__global__ void __launch_bounds__(128, 4) attn(const unsigned short* __restrict__ Q,
                                               const unsigned short* __restrict__ K,
                                               const unsigned short* __restrict__ Vt,
                                               unsigned short* __restrict__ slabA,
                                               unsigned short* __restrict__ slab1,
                                               unsigned short* __restrict__ slab2,
                                               unsigned short* __restrict__ slab3,
                                               float* __restrict__ l0_g,
                                               float* __restrict__ l1_g,
                                               float* __restrict__ l2_g,
                                               float* __restrict__ l3_g) {
  __shared__ unsigned short kbuf[64 * 64];       // [kv][d], swizzled chunks
  __shared__ unsigned short vbuf[64 * 64];       // [d][kv], swizzled chunks

  int bid = blockIdx.x;
  int xcd = bid & 7;                             // dispatch round-robin heuristic
  int kk = bid >> 3;                             // 0..319 within this XCD
  int h = xcd + ((kk >= 160) ? 8 : 0);           // heads h, h+8 pinned to XCD h
  int cidx = (kk >= 160) ? (kk - 160) : kk;      // 0..159
  int j = 159 - cidx;                            // longest chunks first
  int qb, c0, nst, p;
  if (j < 16) {
    qb = j; c0 = 0; nst = qb + 1; p = 0;
  } else if (j < 64) {
    int u = j - 16;
    qb = 16 + (u >> 1);
    int half = u & 1;
    int ntot = qb + 1, nh = (ntot + 1) >> 1;
    p = half;
    if (half) { c0 = nh; nst = ntot - nh; }
    else      { c0 = 0;  nst = nh; }
  } else {
    int u = j - 64;
    qb = 40 + (u >> 2);
    int qt = u & 3;
    int ntot = qb + 1;
    int base = ntot >> 2, rem = ntot & 3;
    c0 = qt * base + (qt < rem ? qt : rem);
    nst = base + (qt < rem ? 1 : 0);
    p = qt;
  }
  bool single = (qb < 16);
  int q0blk = qb * 64;
  int t = threadIdx.x, w = t >> 6, lane = t & 63;
  int col = lane & 15, quad = lane >> 4;
  int q0 = q0blk + w * 32;                       // wave covers 32 q-rows

  const unsigned short* Qh = Q + (size_t)h * S * HD;
  const unsigned short* Kh = K + (size_t)h * S * HD;
  const unsigned short* Vh = Vt + (size_t)h * HD * S;

  // Q^T B-fragments for the 2 q-groups: lane holds Q[q16+col][k-range]
  bf8 qf[2][2];
#pragma unroll
  for (int g = 0; g < 2; g++) {
    qf[g][0] = *(const bf8*)(Qh + (q0 + g * 16 + col) * HD + quad * 8);
    qf[g][1] = *(const bf8*)(Qh + (q0 + g * 16 + col) * HD + 32 + quad * 8);
  }

  f4 o[2][4];
#pragma unroll
  for (int g = 0; g < 2; g++)
#pragma unroll
    for (int dt = 0; dt < 4; dt++) o[g][dt] = (f4){0.f, 0.f, 0.f, 0.f};
  float lsum[2] = {0.f, 0.f};                    // per-lane partial; reduced at end

  int srow = lane >> 3;          // 0..7 within an 8-row staging group
  int sphys = lane & 7;

  for (int s_ = 0; s_ < nst; s_++) {
    int kv0 = (c0 + s_) * 64;
    __syncthreads();             // WAR: prev-step k/v consumers done
#pragma unroll
    for (int pp = 0; pp < 4; pp++) {
      int jj = 4 * w + pp;
      int row = jj * 8 + srow;                 // 0..63
      int lch = sphys ^ (row & 7);
      gld_lds(Kh + (size_t)(kv0 + row) * HD + lch * 8, kbuf + jj * 512);
      gld_lds(Vh + (size_t)row * S + kv0 + lch * 8, vbuf + jj * 512);
    }
    __syncthreads();             // staged data visible

    // ---- scores S^T[kv][q] from LDS K; K-frags shared by both q-groups ----
    f4 st[2][4];
#pragma unroll
    for (int tt = 0; tt < 4; tt++) {
      int kr = tt * 16 + col;
      int sw = col & 7;
      bf8 ka = *(const bf8*)(kbuf + kr * 64 + (quad ^ sw) * 8);
      bf8 kb = *(const bf8*)(kbuf + kr * 64 + ((quad + 4) ^ sw) * 8);
#pragma unroll
      for (int g = 0; g < 2; g++) {
        f4 z = {0.f, 0.f, 0.f, 0.f};
        z = MFMA(ka, qf[g][0], z, 0, 0, 0);
        z = MFMA(kb, qf[g][1], z, 0, 0, 0);
        st[g][tt] = z;
      }
    }

#pragma unroll
    for (int g = 0; g < 2; g++) {
      int q16 = q0 + g * 16;
      if (kv0 + 63 > q16) {                    // diagonal / masked tiles
        int q = q16 + col;
#pragma unroll
        for (int tt = 0; tt < 4; tt++)
#pragma unroll
          for (int rr = 0; rr < 4; rr++) {
            int kv = kv0 + tt * 16 + quad * 4 + rr;
            st[g][tt][rr] = (kv <= q) ? st[g][tt][rr] : -1e30f;
          }
      }
    }

    // ---- fixed-max softmax + in-register P transpose ----
    // st layout: lane(quad,col) holds P[q=col][kv=16tt+4quad+rr].
    // PV A-fragment needs:     lane(quad,col) holds P[q=col][kv=8quad+j].
    // cvt_pk pairs -> permlane32_swap -> permlane16_swap.
    bf8 pf[2][2];
#pragma unroll
    for (int g = 0; g < 2; g++) {
      float pv[4][4];
#pragma unroll
      for (int tt = 0; tt < 4; tt++) {
#pragma unroll
        for (int rr = 0; rr < 4; rr++) pv[tt][rr] = __builtin_amdgcn_exp2f(st[g][tt][rr]);
        lsum[g] += (pv[tt][0] + pv[tt][1]) + (pv[tt][2] + pv[tt][3]);
      }
#pragma unroll
      for (int f = 0; f < 2; f++) {
        unsigned int a0, a1, b0, b1;
        asm("v_cvt_pk_bf16_f32 %0, %1, %2" : "=v"(a0) : "v"(pv[2 * f][0]),     "v"(pv[2 * f][1]));
        asm("v_cvt_pk_bf16_f32 %0, %1, %2" : "=v"(a1) : "v"(pv[2 * f][2]),     "v"(pv[2 * f][3]));
        asm("v_cvt_pk_bf16_f32 %0, %1, %2" : "=v"(b0) : "v"(pv[2 * f + 1][0]), "v"(pv[2 * f + 1][1]));
        asm("v_cvt_pk_bf16_f32 %0, %1, %2" : "=v"(b1) : "v"(pv[2 * f + 1][2]), "v"(pv[2 * f + 1][3]));
        asm("v_permlane32_swap_b32 %0, %1" : "+v"(a0), "+v"(b0));
        asm("v_permlane32_swap_b32 %0, %1" : "+v"(a1), "+v"(b1));
        asm("v_permlane16_swap_b32 %0, %1" : "+v"(a0), "+v"(b0));
        asm("v_permlane16_swap_b32 %0, %1" : "+v"(a1), "+v"(b1));
        u4 pk;
        pk.x = a0; pk.y = a1; pk.z = b0; pk.w = b1;
        pf[g][f] = __builtin_bit_cast(bf8, pk);
      }
    }

    // ---- PV: V-frags shared by both q-groups ----
#pragma unroll
    for (int dt = 0; dt < 4; dt++) {
      int vr = dt * 16 + col;
      int sw = col & 7;
      bf8 v0 = *(const bf8*)(vbuf + vr * 64 + (quad ^ sw) * 8);
      bf8 v1 = *(const bf8*)(vbuf + vr * 64 + ((quad + 4) ^ sw) * 8);
#pragma unroll
      for (int g = 0; g < 2; g++) {
        o[g][dt] = MFMA(pf[g][0], v0, o[g][dt], 0, 0, 0);
        o[g][dt] = MFMA(pf[g][1], v1, o[g][dt], 0, 0, 0);
      }
    }
  }

  // ---- epilogue per q-group: cross-lane l reduce (q = col) ----
#pragma unroll
  for (int g = 0; g < 2; g++) {
    float ls = lsum[g];
    ls += __shfl_xor(ls, 16);
    ls += __shfl_xor(ls, 32);
    int q16 = q0 + g * 16;
    if (single) {
      float inv = 1.0f / ls;
      float ir[4];
#pragma unroll
      for (int rr = 0; rr < 4; rr++) ir[rr] = __shfl(inv, quad * 4 + rr);
#pragma unroll
      for (int dt = 0; dt < 4; dt++)
#pragma unroll
        for (int rr = 0; rr < 4; rr++) {
          int row = q16 + quad * 4 + rr;
          slabA[(size_t)row * DM + h * HD + dt * 16 + col] = f2b(o[g][dt][rr] * ir[rr]);
        }
    } else {
      unsigned short* slab; int rowbase; float* lg;
      if (p == 0)      { slab = slabA; rowbase = q16;        lg = l0_g; }
      else if (p == 1) { slab = slab1; rowbase = q16 - 1024; lg = l1_g; }
      else if (p == 2) { slab = slab2; rowbase = q16 - 2560; lg = l2_g; }
      else             { slab = slab3; rowbase = q16 - 2560; lg = l3_g; }
      if (quad == 0) lg[h * S + q16 + col] = ls;
#pragma unroll
      for (int dt = 0; dt < 4; dt++)
#pragma unroll
        for (int rr = 0; rr < 4; rr++) {
          int row = rowbase + quad * 4 + rr;
          slab[(size_t)row * DM + h * HD + dt * 16 + col] = f2b(o[g][dt][rr]);
        }
    }
  }
}

// ------------- combine bf16 partials -> normalized ctx rows 1024+ -------------
// rows 1024..2559: 2 partials (ctx + slab1); rows 2560..4095: 4 partials.
__global__ void combine(unsigned short* __restrict__ Ctx,
                        const unsigned short* __restrict__ slab1,
                        const unsigned short* __restrict__ slab2,
                        const unsigned short* __restrict__ slab3,
                        const float* __restrict__ l0_g,
                        const float* __restrict__ l1_g,
                        const float* __restrict__ l2_g,
                        const float* __restrict__ l3_g) {
  int row = 1024 + blockIdx.x;
  int cc = threadIdx.x * 4;
  int h = cc >> 6;
  s4 a = *(const s4*)(Ctx + (size_t)row * DM + cc);
  s4 b = *(const s4*)(slab1 + (size_t)(row - 1024) * DM + cc);
  float acc0 = b2f((unsigned short)a.x) + b2f((unsigned short)b.x);
  float acc1 = b2f((unsigned short)a.y) + b2f((unsigned short)b.y);
  float acc2 = b2f((unsigned short)a.z) + b2f((unsigned short)b.z);
  float acc3 = b2f((unsigned short)a.w) + b2f((unsigned short)b.w);
  float l = l0_g[h * S + row] + l1_g[h * S + row];
  if (row >= 2560) {
    s4 c = *(const s4*)(slab2 + (size_t)(row - 2560) * DM + cc);
    s4 d = *(const s4*)(slab3 + (size_t)(row - 2560) * DM + cc);
    acc0 += b2f((unsigned short)c.x) + b2f((unsigned short)d.x);
    acc1 += b2f((unsigned short)c.y) + b2f((unsigned short)d.y);
    acc2 += b2f((unsigned short)c.z) + b2f((unsigned short)d.z);
    acc3 += b2f((unsigned short)c.w) + b2f((unsigned short)d.w);
    l += l2_g[h * S + row] + l3_g[h * S + row];
  }
  float inv = 1.0f / l;
  s4 o;
  o.x = (short)f2b(acc0 * inv);
  o.y = (short)f2b(acc1 * inv);
  o.z = (short)f2b(acc2 * inv);
  o.w = (short)f2b(acc3 * inv);
  *(s4*)(Ctx + (size_t)row * DM + cc) = o;
}

extern "C" void kernel_launch(void* const* d_in, const int* in_sizes, int n_in,
                              void* d_out, int out_size, void* d_ws, size_t ws_size,
                              hipStream_t stream) {
  const float* x     = (const float*)d_in[0];
  const float* w_qkv = (const float*)d_in[1];
  const float* b_qkv = (const float*)d_in[2];
  const float* w_out = (const float*)d_in[3];
  const float* b_out = (const float*)d_in[4];
  float* out = (float*)d_out;

  char* ws = (char*)d_ws;
  unsigned short* xb    = (unsigned short*)(ws);                        //  8 MB (dead after gemm_qkv)
  unsigned short* wqkvT = (unsigned short*)(ws + (size_t)8  * 1048576); //  6 MB (dead after gemm_qkv)
  unsigned short* woutT = (unsigned short*)(ws + (size_t)14 * 1048576); //  2 MB (live till gemm_out)
  unsigned short* Qb    = (unsigned short*)(ws + (size_t)16 * 1048576); //  8 MB
  unsigned short* Kb    = (unsigned short*)(ws + (size_t)24 * 1048576); //  8 MB
  unsigned short* Vtb   = (unsigned short*)(ws + (size_t)32 * 1048576); //  8 MB
  unsigned short* ctx   = (unsigned short*)(ws + (size_t)40 * 1048576); //  8 MB (= slabA)

  // dead-region reuse (gemm_qkv has consumed xb/wqkvT before attn runs):
  // xb region (8MB):    slab1 (rows 1024+, 6MB) + l0..l3 (4 x 256KB)
  // wqkvT region (6MB): slab2 (rows 2560+, 3MB) + slab3 (3MB)
  unsigned short* slab1 = xb;
  float* l0_g = (float*)(ws + (size_t)6 * 1048576);
  float* l1_g = (float*)(ws + (size_t)6 * 1048576 + 256 * 1024);
  float* l2_g = (float*)(ws + (size_t)6 * 1048576 + 512 * 1024);
  float* l3_g = (float*)(ws + (size_t)6 * 1048576 + 768 * 1024);
  unsigned short* slab2 = wqkvT;
  unsigned short* slab3 = (unsigned short*)(ws + (size_t)11 * 1048576);

  prep<<<5120, 256, 0, stream>>>(x, w_qkv, w_out, xb, wqkvT, woutT);
  gemm_qkv<<<64 * 24, 256, 0, stream>>>(xb, wqkvT, b_qkv, Qb, Kb, Vtb);
  attn<<<NH * 160, 128, 0, stream>>>(Qb, Kb, Vtb, ctx, slab1, slab2, slab3,
                                     l0_g, l1_g, l2_g, l3_g);
  combine<<<3072, 256, 0, stream>>>(ctx, slab1, slab2, slab3, l0_g, l1_g, l2_g, l3_g);
  gemm_out<<<64 * 16, 256, 0, stream>>>(ctx, woutT, b_out, out);
}

// Round 10
// 187.810 us; speedup vs baseline: 1.6559x; 1.0439x over previous
//
#include <hip/hip_runtime.h>

#define S 4096
#define DM 1024
#define NH 16
#define HD 64

typedef __attribute__((ext_vector_type(8))) short bf8;
typedef __attribute__((ext_vector_type(4))) float f4;
typedef __attribute__((ext_vector_type(4))) short s4;
typedef __attribute__((ext_vector_type(4))) unsigned int u4;

#define MFMA __builtin_amdgcn_mfma_f32_16x16x32_bf16

// softmax scale folded into Q, in base-2 domain: 1/sqrt(64) * log2(e)
#define QSCALE 0.18033688011112042f

static __device__ __forceinline__ unsigned short f2b(float f) {
  unsigned int u = __builtin_bit_cast(unsigned int, f);
  u += 0x7fffu + ((u >> 16) & 1u);   // RNE
  return (unsigned short)(u >> 16);
}
static __device__ __forceinline__ float b2f(unsigned short u) {
  return __builtin_bit_cast(float, (unsigned int)u << 16);
}

// async global->LDS, 16B per lane. LDS dest must be WAVE-UNIFORM base;
// HW scatters lane i to base + i*16.
static __device__ __forceinline__ void gld_lds(const unsigned short* g, unsigned short* l) {
  __builtin_amdgcn_global_load_lds(
      (const __attribute__((address_space(1))) unsigned int*)g,
      (__attribute__((address_space(3))) unsigned int*)l, 16, 0, 0);
}

// ------------- fused prep: cast x->bf16 ; transpose+cast w_qkv, w_out -------------
// blocks 0..4095: cast x (4M elems). 4096..4863: wqkvT tiles. 4864..5119: woutT tiles.
__global__ void prep(const float* __restrict__ x, const float* __restrict__ w_qkv,
                     const float* __restrict__ w_out,
                     unsigned short* __restrict__ xb, unsigned short* __restrict__ wqkvT,
                     unsigned short* __restrict__ woutT) {
  __shared__ float tile[64][65];
  int b = blockIdx.x, t = threadIdx.x;
  if (b < 4096) {
    int i = (b * 256 + t) * 4;
    float4 v = *(const float4*)(x + i);
    s4 o;
    o.x = (short)f2b(v.x); o.y = (short)f2b(v.y);
    o.z = (short)f2b(v.z); o.w = (short)f2b(v.w);
    *(s4*)(xb + i) = o;
    return;
  }
  const float* in; unsigned short* out; int R, C, tc, tr;
  if (b < 4096 + 768) { int bb = b - 4096; in = w_qkv; out = wqkvT; R = DM; C = 3 * DM; tc = bb % 48; tr = bb / 48; }
  else                { int bb = b - 4864; in = w_out; out = woutT; R = DM; C = DM;     tc = bb % 16; tr = bb / 16; }
  int c = t & 63, rbase = (t >> 6) * 16;
#pragma unroll
  for (int i = 0; i < 16; i++) {
    int r = rbase + i;
    tile[r][c] = in[(tr * 64 + r) * C + tc * 64 + c];
  }
  __syncthreads();
#pragma unroll
  for (int i = 0; i < 16; i++) {
    int cc = rbase + i;
    out[(tc * 64 + cc) * R + tr * 64 + c] = f2b(tile[c][cc]);
  }
}

// =================================================================
// GEMM cores — reverted to the R7-proven forms (194.0us config).
// =================================================================

// ------------- QKV GEMM + scatter epilogue (128x128, BK=64, 4 waves) -------------
__global__ void __launch_bounds__(256, 2) gemm_qkv(const unsigned short* __restrict__ A,
                                                   const unsigned short* __restrict__ Bt,
                                                   const float* __restrict__ bias,
                                                   unsigned short* __restrict__ Qo,
                                                   unsigned short* __restrict__ Ko,
                                                   unsigned short* __restrict__ Vt) {
  __shared__ unsigned short lA[128 * 64];   // 16 KB, [row][64] swizzled chunks
  __shared__ unsigned short lB[128 * 64];   // 16 KB
  int bid = blockIdx.x;
  int nb = bid % 24, mb = bid / 24;
  int m0 = mb * 128, n0 = nb * 128;
  int t = threadIdx.x, w = t >> 6, lane = t & 63;
  int col = lane & 15, quad = lane >> 4;
  int wm = (w >> 1) * 64, wn = (w & 1) * 64;

  int srow = lane >> 3;          // 0..7 within an 8-row staging group
  int sphys = lane & 7;

  f4 acc[4][4];
#pragma unroll
  for (int x = 0; x < 4; x++)
#pragma unroll
    for (int y = 0; y < 4; y++) acc[x][y] = (f4){0.f, 0.f, 0.f, 0.f};

  for (int k0 = 0; k0 < DM; k0 += 64) {
    __syncthreads();   // WAR: prev-step consumers done
#pragma unroll
    for (int p = 0; p < 4; p++) {
      int j = 4 * w + p;                       // 16 groups of 8 rows
      int row = j * 8 + srow;                  // 0..127
      int lch = sphys ^ (row & 7);             // logical 16B chunk to fetch
      gld_lds(A + (size_t)(m0 + row) * DM + k0 + lch * 8, lA + j * 512);
      gld_lds(Bt + (size_t)(n0 + row) * DM + k0 + lch * 8, lB + j * 512);
    }
    __syncthreads();   // staged data visible

#pragma unroll
    for (int ks = 0; ks < 2; ks++) {
      bf8 af[4], bfr[4];
      int sw = col & 7;
#pragma unroll
      for (int x = 0; x < 4; x++) {
        int rA = wm + x * 16 + col;
        af[x] = *(const bf8*)(lA + rA * 64 + ((quad + 4 * ks) ^ sw) * 8);
        int rB = wn + x * 16 + col;
        bfr[x] = *(const bf8*)(lB + rB * 64 + ((quad + 4 * ks) ^ sw) * 8);
      }
#pragma unroll
      for (int x = 0; x < 4; x++)
#pragma unroll
        for (int y = 0; y < 4; y++)
          acc[x][y] = MFMA(af[x], bfr[y], acc[x][y], 0, 0, 0);
    }
  }

  // epilogue: scatter to Q (scaled), K, Vt
#pragma unroll
  for (int x = 0; x < 4; x++) {
    int s0r = m0 + wm + x * 16 + quad * 4;
#pragma unroll
    for (int y = 0; y < 4; y++) {
      f4 a = acc[x][y];
      int n = n0 + wn + y * 16 + col;
      float bv = bias[n];
      if (n < 2048) {
        unsigned short* dst = (n < 1024) ? Qo : Ko;
        float sc = (n < 1024) ? QSCALE : 1.0f;
        int nn = n & 1023;
        int hh = nn >> 6, d = nn & 63;
        unsigned short* pp = dst + ((size_t)hh * S + s0r) * HD + d;
#pragma unroll
        for (int r = 0; r < 4; r++) pp[r * HD] = f2b((a[r] + bv) * sc);
      } else {
        int nn = n - 2048;
        int hh = nn >> 6, d = nn & 63;
        s4 pk;
        pk.x = (short)f2b(a[0] + bv);
        pk.y = (short)f2b(a[1] + bv);
        pk.z = (short)f2b(a[2] + bv);
        pk.w = (short)f2b(a[3] + bv);
        *(s4*)(Vt + ((size_t)hh * HD + d) * S + s0r) = pk;
      }
    }
  }
}

// ------------- Out GEMM: ctx x woutT + bias -> fp32 (64x128, BK=64) -------------
__global__ void __launch_bounds__(256, 2) gemm_out(const unsigned short* __restrict__ A,
                                                   const unsigned short* __restrict__ Bt,
                                                   const float* __restrict__ bias,
                                                   float* __restrict__ out) {
  __shared__ unsigned short lA[64 * 64];    //  8 KB
  __shared__ unsigned short lB[128 * 64];   // 16 KB
  int bid = blockIdx.x;
  int nb = bid % 8, mb = bid / 8;              // mb 0..63; nb==bid%8 -> per-XCD B-panel affinity
  int m0 = mb * 64, n0 = nb * 128;
  int t = threadIdx.x, w = t >> 6, lane = t & 63;
  int col = lane & 15, quad = lane >> 4;
  int wm = (w >> 1) * 32, wn = (w & 1) * 64;

  int srow = lane >> 3;
  int sphys = lane & 7;

  f4 acc[2][4];
#pragma unroll
  for (int x = 0; x < 2; x++)
#pragma unroll
    for (int y = 0; y < 4; y++) acc[x][y] = (f4){0.f, 0.f, 0.f, 0.f};

  for (int k0 = 0; k0 < DM; k0 += 64) {
    __syncthreads();
#pragma unroll
    for (int p = 0; p < 2; p++) {
      int j = 2 * w + p;                       // A: 8 groups of 8 rows
      int row = j * 8 + srow;                  // 0..63
      int lch = sphys ^ (row & 7);
      gld_lds(A + (size_t)(m0 + row) * DM + k0 + lch * 8, lA + j * 512);
    }
#pragma unroll
    for (int p = 0; p < 4; p++) {
      int j = 4 * w + p;                       // B: 16 groups of 8 rows
      int row = j * 8 + srow;                  // 0..127
      int lch = sphys ^ (row & 7);
      gld_lds(Bt + (size_t)(n0 + row) * DM + k0 + lch * 8, lB + j * 512);
    }
    __syncthreads();

#pragma unroll
    for (int ks = 0; ks < 2; ks++) {
      bf8 af[2], bfr[4];
      int sw = col & 7;
#pragma unroll
      for (int x = 0; x < 2; x++) {
        int rA = wm + x * 16 + col;
        af[x] = *(const bf8*)(lA + rA * 64 + ((quad + 4 * ks) ^ sw) * 8);
      }
#pragma unroll
      for (int y = 0; y < 4; y++) {
        int rB = wn + y * 16 + col;
        bfr[y] = *(const bf8*)(lB + rB * 64 + ((quad + 4 * ks) ^ sw) * 8);
      }
#pragma unroll
      for (int x = 0; x < 2; x++)
#pragma unroll
        for (int y = 0; y < 4; y++)
          acc[x][y] = MFMA(af[x], bfr[y], acc[x][y], 0, 0, 0);
    }
  }

#pragma unroll
  for (int x = 0; x < 2; x++) {
    int s0r = m0 + wm + x * 16 + quad * 4;
#pragma unroll
    for (int y = 0; y < 4; y++) {
      f4 a = acc[x][y];
      int n = n0 + wn + y * 16 + col;
      float bv = bias[n];
#pragma unroll
      for (int r = 0; r < 4; r++) out[(size_t)(s0r + r) * DM + n] = a[r] + bv;
    }
  }
}

// =================================================================
// Split-KV flash attention, fixed-max (m=0) softmax.
// R10: 4-wave (256-thread) blocks, 128 q-rows per block. Each wave
// keeps the proven 32-row / 64-VGPR body; the staged 16KB K/V tile
// now feeds 4 waves instead of 2 -> staging drains halve (33280 ->
// 16896 events). 16KB LDS + 64 VGPR => 8 blocks/CU cap; grid 1280 =
// 5/CU -> ENTIRE GRID CO-RESIDENT (no dispatch tail).
// Schedule per head: 32 q-blocks of 128 rows; split-KV 1-way (qb<8,
// rows<1024), 2-way (qb 8..19, rows 1024..2559), 4-way (qb 20..31,
// rows 2560..4095) — same row boundaries as before, combine & slabs
// unchanged. Head->XCD affinity kept (K/V L2-resident, FETCH ~12MB).
// =================================================================
__global__ void __launch_bounds__(256, 4) attn(const unsigned short* __restrict__ Q,
                                               const unsigned short* __restrict__ K,
                                               const unsigned short* __restrict__ Vt,
                                               unsigned short* __restrict__ slabA,
                                               unsigned short* __restrict__ slab1,
                                               unsigned short* __restrict__ slab2,
                                               unsigned short* __restrict__ slab3,
                                               float* __restrict__ l0_g,
                                               float* __restrict__ l1_g,
                                               float* __restrict__ l2_g,
                                               float* __restrict__ l3_g) {
  __shared__ unsigned short kbuf[64 * 64];       // [kv][d], swizzled chunks
  __shared__ unsigned short vbuf[64 * 64];       // [d][kv], swizzled chunks

  int bid = blockIdx.x;
  int xcd = bid & 7;                             // dispatch round-robin heuristic
  int kk = bid >> 3;                             // 0..159 within this XCD
  int h = xcd + ((kk >= 80) ? 8 : 0);            // heads h, h+8 pinned to XCD h
  int cidx = (kk >= 80) ? (kk - 80) : kk;        // 0..79
  int j = 79 - cidx;                             // longest chunks first
  int qb, c0, nst, p;
  if (j < 8) {
    qb = j; c0 = 0; nst = 2 * qb + 2; p = 0;
  } else if (j < 32) {
    int u = j - 8;
    qb = 8 + (u >> 1);
    int half = u & 1;
    int nh = qb + 1;                             // ntot = 2qb+2, even split
    p = half;
    c0 = half ? nh : 0;
    nst = nh;
  } else {
    int u = j - 32;
    qb = 20 + (u >> 2);
    int qt = u & 3;
    int ntot = 2 * qb + 2;
    int base = ntot >> 2, rem = ntot & 3;
    c0 = qt * base + (qt < rem ? qt : rem);
    nst = base + (qt < rem ? 1 : 0);
    p = qt;
  }
  bool single = (j < 8);
  int q0blk = qb * 128;
  int t = threadIdx.x, w = t >> 6, lane = t & 63;
  int col = lane & 15, quad = lane >> 4;
  int q0 = q0blk + w * 32;                       // wave covers 32 q-rows

  const unsigned short* Qh = Q + (size_t)h * S * HD;
  const unsigned short* Kh = K + (size_t)h * S * HD;
  const unsigned short* Vh = Vt + (size_t)h * HD * S;

  // Q^T B-fragments for the 2 q-groups: lane holds Q[q16+col][k-range]
  bf8 qf[2][2];
#pragma unroll
  for (int g = 0; g < 2; g++) {
    qf[g][0] = *(const bf8*)(Qh + (q0 + g * 16 + col) * HD + quad * 8);
    qf[g][1] = *(const bf8*)(Qh + (q0 + g * 16 + col) * HD + 32 + quad * 8);
  }

  f4 o[2][4];
#pragma unroll
  for (int g = 0; g < 2; g++)
#pragma unroll
    for (int dt = 0; dt < 4; dt++) o[g][dt] = (f4){0.f, 0.f, 0.f, 0.f};
  float lsum[2] = {0.f, 0.f};                    // per-lane partial; reduced at end

  int srow = lane >> 3;          // 0..7 within an 8-row staging group
  int sphys = lane & 7;

  for (int s_ = 0; s_ < nst; s_++) {
    int kv0 = (c0 + s_) * 64;
    __syncthreads();             // WAR: prev-step k/v consumers done
#pragma unroll
    for (int pp = 0; pp < 2; pp++) {
      int jj = 2 * w + pp;                     // 8 groups across 4 waves
      int row = jj * 8 + srow;                 // 0..63
      int lch = sphys ^ (row & 7);
      gld_lds(Kh + (size_t)(kv0 + row) * HD + lch * 8, kbuf + jj * 512);
      gld_lds(Vh + (size_t)row * S + kv0 + lch * 8, vbuf + jj * 512);
    }
    __syncthreads();             // staged data visible

    // ---- scores S^T[kv][q] from LDS K; K-frags shared by both q-groups ----
    f4 st[2][4];
#pragma unroll
    for (int tt = 0; tt < 4; tt++) {
      int kr = tt * 16 + col;
      int sw = col & 7;
      bf8 ka = *(const bf8*)(kbuf + kr * 64 + (quad ^ sw) * 8);
      bf8 kb = *(const bf8*)(kbuf + kr * 64 + ((quad + 4) ^ sw) * 8);
#pragma unroll
      for (int g = 0; g < 2; g++) {
        f4 z = {0.f, 0.f, 0.f, 0.f};
        z = MFMA(ka, qf[g][0], z, 0, 0, 0);
        z = MFMA(kb, qf[g][1], z, 0, 0, 0);
        st[g][tt] = z;
      }
    }

#pragma unroll
    for (int g = 0; g < 2; g++) {
      int q16 = q0 + g * 16;
      if (kv0 + 63 > q16) {                    // diagonal / masked tiles
        int q = q16 + col;
#pragma unroll
        for (int tt = 0; tt < 4; tt++)
#pragma unroll
          for (int rr = 0; rr < 4; rr++) {
            int kv = kv0 + tt * 16 + quad * 4 + rr;
            st[g][tt][rr] = (kv <= q) ? st[g][tt][rr] : -1e30f;
          }
      }
    }

    // ---- fixed-max softmax + in-register P transpose ----
    // st layout: lane(quad,col) holds P[q=col][kv=16tt+4quad+rr].
    // PV A-fragment needs:     lane(quad,col) holds P[q=col][kv=8quad+j].
    // cvt_pk pairs -> permlane32_swap -> permlane16_swap.
    bf8 pf[2][2];
#pragma unroll
    for (int g = 0; g < 2; g++) {
      float pv[4][4];
#pragma unroll
      for (int tt = 0; tt < 4; tt++) {
#pragma unroll
        for (int rr = 0; rr < 4; rr++) pv[tt][rr] = __builtin_amdgcn_exp2f(st[g][tt][rr]);
        lsum[g] += (pv[tt][0] + pv[tt][1]) + (pv[tt][2] + pv[tt][3]);
      }
#pragma unroll
      for (int f = 0; f < 2; f++) {
        unsigned int a0, a1, b0, b1;
        asm("v_cvt_pk_bf16_f32 %0, %1, %2" : "=v"(a0) : "v"(pv[2 * f][0]),     "v"(pv[2 * f][1]));
        asm("v_cvt_pk_bf16_f32 %0, %1, %2" : "=v"(a1) : "v"(pv[2 * f][2]),     "v"(pv[2 * f][3]));
        asm("v_cvt_pk_bf16_f32 %0, %1, %2" : "=v"(b0) : "v"(pv[2 * f + 1][0]), "v"(pv[2 * f + 1][1]));
        asm("v_cvt_pk_bf16_f32 %0, %1, %2" : "=v"(b1) : "v"(pv[2 * f + 1][2]), "v"(pv[2 * f + 1][3]));
        asm("v_permlane32_swap_b32 %0, %1" : "+v"(a0), "+v"(b0));
        asm("v_permlane32_swap_b32 %0, %1" : "+v"(a1), "+v"(b1));
        asm("v_permlane16_swap_b32 %0, %1" : "+v"(a0), "+v"(b0));
        asm("v_permlane16_swap_b32 %0, %1" : "+v"(a1), "+v"(b1));
        u4 pk;
        pk.x = a0; pk.y = a1; pk.z = b0; pk.w = b1;
        pf[g][f] = __builtin_bit_cast(bf8, pk);
      }
    }

    // ---- PV: V-frags shared by both q-groups ----
#pragma unroll
    for (int dt = 0; dt < 4; dt++) {
      int vr = dt * 16 + col;
      int sw = col & 7;
      bf8 v0 = *(const bf8*)(vbuf + vr * 64 + (quad ^ sw) * 8);
      bf8 v1 = *(const bf8*)(vbuf + vr * 64 + ((quad + 4) ^ sw) * 8);
#pragma unroll
      for (int g = 0; g < 2; g++) {
        o[g][dt] = MFMA(pf[g][0], v0, o[g][dt], 0, 0, 0);
        o[g][dt] = MFMA(pf[g][1], v1, o[g][dt], 0, 0, 0);
      }
    }
  }

  // ---- epilogue per q-group: cross-lane l reduce (q = col) ----
#pragma unroll
  for (int g = 0; g < 2; g++) {
    float ls = lsum[g];
    ls += __shfl_xor(ls, 16);
    ls += __shfl_xor(ls, 32);
    int q16 = q0 + g * 16;
    if (single) {
      float inv = 1.0f / ls;
      float ir[4];
#pragma unroll
      for (int rr = 0; rr < 4; rr++) ir[rr] = __shfl(inv, quad * 4 + rr);
#pragma unroll
      for (int dt = 0; dt < 4; dt++)
#pragma unroll
        for (int rr = 0; rr < 4; rr++) {
          int row = q16 + quad * 4 + rr;
          slabA[(size_t)row * DM + h * HD + dt * 16 + col] = f2b(o[g][dt][rr] * ir[rr]);
        }
    } else {
      unsigned short* slab; int rowbase; float* lg;
      if (p == 0)      { slab = slabA; rowbase = q16;        lg = l0_g; }
      else if (p == 1) { slab = slab1; rowbase = q16 - 1024; lg = l1_g; }
      else if (p == 2) { slab = slab2; rowbase = q16 - 2560; lg = l2_g; }
      else             { slab = slab3; rowbase = q16 - 2560; lg = l3_g; }
      if (quad == 0) lg[h * S + q16 + col] = ls;
#pragma unroll
      for (int dt = 0; dt < 4; dt++)
#pragma unroll
        for (int rr = 0; rr < 4; rr++) {
          int row = rowbase + quad * 4 + rr;
          slab[(size_t)row * DM + h * HD + dt * 16 + col] = f2b(o[g][dt][rr]);
        }
    }
  }
}

// ------------- combine bf16 partials -> normalized ctx rows 1024+ -------------
// rows 1024..2559: 2 partials (ctx + slab1); rows 2560..4095: 4 partials.
__global__ void combine(unsigned short* __restrict__ Ctx,
                        const unsigned short* __restrict__ slab1,
                        const unsigned short* __restrict__ slab2,
                        const unsigned short* __restrict__ slab3,
                        const float* __restrict__ l0_g,
                        const float* __restrict__ l1_g,
                        const float* __restrict__ l2_g,
                        const float* __restrict__ l3_g) {
  int row = 1024 + blockIdx.x;
  int cc = threadIdx.x * 4;
  int h = cc >> 6;
  s4 a = *(const s4*)(Ctx + (size_t)row * DM + cc);
  s4 b = *(const s4*)(slab1 + (size_t)(row - 1024) * DM + cc);
  float acc0 = b2f((unsigned short)a.x) + b2f((unsigned short)b.x);
  float acc1 = b2f((unsigned short)a.y) + b2f((unsigned short)b.y);
  float acc2 = b2f((unsigned short)a.z) + b2f((unsigned short)b.z);
  float acc3 = b2f((unsigned short)a.w) + b2f((unsigned short)b.w);
  float l = l0_g[h * S + row] + l1_g[h * S + row];
  if (row >= 2560) {
    s4 c = *(const s4*)(slab2 + (size_t)(row - 2560) * DM + cc);
    s4 d = *(const s4*)(slab3 + (size_t)(row - 2560) * DM + cc);
    acc0 += b2f((unsigned short)c.x) + b2f((unsigned short)d.x);
    acc1 += b2f((unsigned short)c.y) + b2f((unsigned short)d.y);
    acc2 += b2f((unsigned short)c.z) + b2f((unsigned short)d.z);
    acc3 += b2f((unsigned short)c.w) + b2f((unsigned short)d.w);
    l += l2_g[h * S + row] + l3_g[h * S + row];
  }
  float inv = 1.0f / l;
  s4 o;
  o.x = (short)f2b(acc0 * inv);
  o.y = (short)f2b(acc1 * inv);
  o.z = (short)f2b(acc2 * inv);
  o.w = (short)f2b(acc3 * inv);
  *(s4*)(Ctx + (size_t)row * DM + cc) = o;
}

extern "C" void kernel_launch(void* const* d_in, const int* in_sizes, int n_in,
                              void* d_out, int out_size, void* d_ws, size_t ws_size,
                              hipStream_t stream) {
  const float* x     = (const float*)d_in[0];
  const float* w_qkv = (const float*)d_in[1];
  const float* b_qkv = (const float*)d_in[2];
  const float* w_out = (const float*)d_in[3];
  const float* b_out = (const float*)d_in[4];
  float* out = (float*)d_out;

  char* ws = (char*)d_ws;
  unsigned short* xb    = (unsigned short*)(ws);                        //  8 MB (dead after gemm_qkv)
  unsigned short* wqkvT = (unsigned short*)(ws + (size_t)8  * 1048576); //  6 MB (dead after gemm_qkv)
  unsigned short* woutT = (unsigned short*)(ws + (size_t)14 * 1048576); //  2 MB (live till gemm_out)
  unsigned short* Qb    = (unsigned short*)(ws + (size_t)16 * 1048576); //  8 MB
  unsigned short* Kb    = (unsigned short*)(ws + (size_t)24 * 1048576); //  8 MB
  unsigned short* Vtb   = (unsigned short*)(ws + (size_t)32 * 1048576); //  8 MB
  unsigned short* ctx   = (unsigned short*)(ws + (size_t)40 * 1048576); //  8 MB (= slabA)

  // dead-region reuse (gemm_qkv has consumed xb/wqkvT before attn runs):
  // xb region (8MB):    slab1 (rows 1024+, 6MB) + l0..l3 (4 x 256KB)
  // wqkvT region (6MB): slab2 (rows 2560+, 3MB) + slab3 (3MB)
  unsigned short* slab1 = xb;
  float* l0_g = (float*)(ws + (size_t)6 * 1048576);
  float* l1_g = (float*)(ws + (size_t)6 * 1048576 + 256 * 1024);
  float* l2_g = (float*)(ws + (size_t)6 * 1048576 + 512 * 1024);
  float* l3_g = (float*)(ws + (size_t)6 * 1048576 + 768 * 1024);
  unsigned short* slab2 = wqkvT;
  unsigned short* slab3 = (unsigned short*)(ws + (size_t)11 * 1048576);

  prep<<<5120, 256, 0, stream>>>(x, w_qkv, w_out, xb, wqkvT, woutT);
  gemm_qkv<<<32 * 24, 256, 0, stream>>>(xb, wqkvT, b_qkv, Qb, Kb, Vtb);
  attn<<<1280, 256, 0, stream>>>(Qb, Kb, Vtb, ctx, slab1, slab2, slab3,
                                 l0_g, l1_g, l2_g, l3_g);
  combine<<<3072, 256, 0, stream>>>(ctx, slab1, slab2, slab3, l0_g, l1_g, l2_g, l3_g);
  gemm_out<<<64 * 8, 256, 0, stream>>>(ctx, woutT, b_out, out);
}

// Round 12
// 186.802 us; speedup vs baseline: 1.6648x; 1.0054x over previous
//
#include <hip/hip_runtime.h>

#define S 4096
#define DM 1024
#define NH 16
#define HD 64

typedef __attribute__((ext_vector_type(8))) short bf8;
typedef __attribute__((ext_vector_type(4))) float f4;
typedef __attribute__((ext_vector_type(4))) short s4;
typedef __attribute__((ext_vector_type(4))) unsigned int u4;

#define MFMA __builtin_amdgcn_mfma_f32_16x16x32_bf16

// softmax scale folded into Q, in base-2 domain: 1/sqrt(64) * log2(e)
#define QSCALE 0.18033688011112042f

static __device__ __forceinline__ unsigned short f2b(float f) {
  unsigned int u = __builtin_bit_cast(unsigned int, f);
  u += 0x7fffu + ((u >> 16) & 1u);   // RNE
  return (unsigned short)(u >> 16);
}
static __device__ __forceinline__ float b2f(unsigned short u) {
  return __builtin_bit_cast(float, (unsigned int)u << 16);
}

// async global->LDS, 16B per lane. LDS dest must be WAVE-UNIFORM base;
// HW scatters lane i to base + i*16.
static __device__ __forceinline__ void gld_lds(const unsigned short* g, unsigned short* l) {
  __builtin_amdgcn_global_load_lds(
      (const __attribute__((address_space(1))) unsigned int*)g,
      (__attribute__((address_space(3))) unsigned int*)l, 16, 0, 0);
}

// ------------- fused prep: cast x->bf16 ; transpose+cast w_qkv, w_out -------------
// blocks 0..4095: cast x (4M elems). 4096..4863: wqkvT tiles. 4864..5119: woutT tiles.
__global__ void prep(const float* __restrict__ x, const float* __restrict__ w_qkv,
                     const float* __restrict__ w_out,
                     unsigned short* __restrict__ xb, unsigned short* __restrict__ wqkvT,
                     unsigned short* __restrict__ woutT) {
  __shared__ float tile[64][65];
  int b = blockIdx.x, t = threadIdx.x;
  if (b < 4096) {
    int i = (b * 256 + t) * 4;
    float4 v = *(const float4*)(x + i);
    s4 o;
    o.x = (short)f2b(v.x); o.y = (short)f2b(v.y);
    o.z = (short)f2b(v.z); o.w = (short)f2b(v.w);
    *(s4*)(xb + i) = o;
    return;
  }
  const float* in; unsigned short* out; int R, C, tc, tr;
  if (b < 4096 + 768) { int bb = b - 4096; in = w_qkv; out = wqkvT; R = DM; C = 3 * DM; tc = bb % 48; tr = bb / 48; }
  else                { int bb = b - 4864; in = w_out; out = woutT; R = DM; C = DM;     tc = bb % 16; tr = bb / 16; }
  int c = t & 63, rbase = (t >> 6) * 16;
#pragma unroll
  for (int i = 0; i < 16; i++) {
    int r = rbase + i;
    tile[r][c] = in[(tr * 64 + r) * C + tc * 64 + c];
  }
  __syncthreads();
#pragma unroll
  for (int i = 0; i < 16; i++) {
    int cc = rbase + i;
    out[(tc * 64 + cc) * R + tr * 64 + c] = f2b(tile[c][cc]);
  }
}

// =================================================================
// GEMM cores — frozen at the R10/187.8us config.
// =================================================================

// ------------- QKV GEMM + scatter epilogue (128x128, BK=64, 4 waves) -------------
__global__ void __launch_bounds__(256, 2) gemm_qkv(const unsigned short* __restrict__ A,
                                                   const unsigned short* __restrict__ Bt,
                                                   const float* __restrict__ bias,
                                                   unsigned short* __restrict__ Qo,
                                                   unsigned short* __restrict__ Ko,
                                                   unsigned short* __restrict__ Vt) {
  __shared__ unsigned short lA[128 * 64];   // 16 KB, [row][64] swizzled chunks
  __shared__ unsigned short lB[128 * 64];   // 16 KB
  int bid = blockIdx.x;
  int nb = bid % 24, mb = bid / 24;
  int m0 = mb * 128, n0 = nb * 128;
  int t = threadIdx.x, w = t >> 6, lane = t & 63;
  int col = lane & 15, quad = lane >> 4;
  int wm = (w >> 1) * 64, wn = (w & 1) * 64;

  int srow = lane >> 3;          // 0..7 within an 8-row staging group
  int sphys = lane & 7;

  f4 acc[4][4];
#pragma unroll
  for (int x = 0; x < 4; x++)
#pragma unroll
    for (int y = 0; y < 4; y++) acc[x][y] = (f4){0.f, 0.f, 0.f, 0.f};

  for (int k0 = 0; k0 < DM; k0 += 64) {
    __syncthreads();   // WAR: prev-step consumers done
#pragma unroll
    for (int p = 0; p < 4; p++) {
      int j = 4 * w + p;                       // 16 groups of 8 rows
      int row = j * 8 + srow;                  // 0..127
      int lch = sphys ^ (row & 7);             // logical 16B chunk to fetch
      gld_lds(A + (size_t)(m0 + row) * DM + k0 + lch * 8, lA + j * 512);
      gld_lds(Bt + (size_t)(n0 + row) * DM + k0 + lch * 8, lB + j * 512);
    }
    __syncthreads();   // staged data visible

#pragma unroll
    for (int ks = 0; ks < 2; ks++) {
      bf8 af[4], bfr[4];
      int sw = col & 7;
#pragma unroll
      for (int x = 0; x < 4; x++) {
        int rA = wm + x * 16 + col;
        af[x] = *(const bf8*)(lA + rA * 64 + ((quad + 4 * ks) ^ sw) * 8);
        int rB = wn + x * 16 + col;
        bfr[x] = *(const bf8*)(lB + rB * 64 + ((quad + 4 * ks) ^ sw) * 8);
      }
#pragma unroll
      for (int x = 0; x < 4; x++)
#pragma unroll
        for (int y = 0; y < 4; y++)
          acc[x][y] = MFMA(af[x], bfr[y], acc[x][y], 0, 0, 0);
    }
  }

  // epilogue: scatter to Q (scaled), K, Vt
#pragma unroll
  for (int x = 0; x < 4; x++) {
    int s0r = m0 + wm + x * 16 + quad * 4;
#pragma unroll
    for (int y = 0; y < 4; y++) {
      f4 a = acc[x][y];
      int n = n0 + wn + y * 16 + col;
      float bv = bias[n];
      if (n < 2048) {
        unsigned short* dst = (n < 1024) ? Qo : Ko;
        float sc = (n < 1024) ? QSCALE : 1.0f;
        int nn = n & 1023;
        int hh = nn >> 6, d = nn & 63;
        unsigned short* pp = dst + ((size_t)hh * S + s0r) * HD + d;
#pragma unroll
        for (int r = 0; r < 4; r++) pp[r * HD] = f2b((a[r] + bv) * sc);
      } else {
        int nn = n - 2048;
        int hh = nn >> 6, d = nn & 63;
        s4 pk;
        pk.x = (short)f2b(a[0] + bv);
        pk.y = (short)f2b(a[1] + bv);
        pk.z = (short)f2b(a[2] + bv);
        pk.w = (short)f2b(a[3] + bv);
        *(s4*)(Vt + ((size_t)hh * HD + d) * S + s0r) = pk;
      }
    }
  }
}

// ------------- Out GEMM: ctx x woutT + bias -> fp32 (64x128, BK=64) -------------
__global__ void __launch_bounds__(256, 2) gemm_out(const unsigned short* __restrict__ A,
                                                   const unsigned short* __restrict__ Bt,
                                                   const float* __restrict__ bias,
                                                   float* __restrict__ out) {
  __shared__ unsigned short lA[64 * 64];    //  8 KB
  __shared__ unsigned short lB[128 * 64];   // 16 KB
  int bid = blockIdx.x;
  int nb = bid % 8, mb = bid / 8;              // mb 0..63; nb==bid%8 -> per-XCD B-panel affinity
  int m0 = mb * 64, n0 = nb * 128;
  int t = threadIdx.x, w = t >> 6, lane = t & 63;
  int col = lane & 15, quad = lane >> 4;
  int wm = (w >> 1) * 32, wn = (w & 1) * 64;

  int srow = lane >> 3;
  int sphys = lane & 7;

  f4 acc[2][4];
#pragma unroll
  for (int x = 0; x < 2; x++)
#pragma unroll
    for (int y = 0; y < 4; y++) acc[x][y] = (f4){0.f, 0.f, 0.f, 0.f};

  for (int k0 = 0; k0 < DM; k0 += 64) {
    __syncthreads();
#pragma unroll
    for (int p = 0; p < 2; p++) {
      int j = 2 * w + p;                       // A: 8 groups of 8 rows
      int row = j * 8 + srow;                  // 0..63
      int lch = sphys ^ (row & 7);
      gld_lds(A + (size_t)(m0 + row) * DM + k0 + lch * 8, lA + j * 512);
    }
#pragma unroll
    for (int p = 0; p < 4; p++) {
      int j = 4 * w + p;                       // B: 16 groups of 8 rows
      int row = j * 8 + srow;                  // 0..127
      int lch = sphys ^ (row & 7);
      gld_lds(Bt + (size_t)(n0 + row) * DM + k0 + lch * 8, lB + j * 512);
    }
    __syncthreads();

#pragma unroll
    for (int ks = 0; ks < 2; ks++) {
      bf8 af[2], bfr[4];
      int sw = col & 7;
#pragma unroll
      for (int x = 0; x < 2; x++) {
        int rA = wm + x * 16 + col;
        af[x] = *(const bf8*)(lA + rA * 64 + ((quad + 4 * ks) ^ sw) * 8);
      }
#pragma unroll
      for (int y = 0; y < 4; y++) {
        int rB = wn + y * 16 + col;
        bfr[y] = *(const bf8*)(lB + rB * 64 + ((quad + 4 * ks) ^ sw) * 8);
      }
#pragma unroll
      for (int x = 0; x < 2; x++)
#pragma unroll
        for (int y = 0; y < 4; y++)
          acc[x][y] = MFMA(af[x], bfr[y], acc[x][y], 0, 0, 0);
    }
  }

#pragma unroll
  for (int x = 0; x < 2; x++) {
    int s0r = m0 + wm + x * 16 + quad * 4;
#pragma unroll
    for (int y = 0; y < 4; y++) {
      f4 a = acc[x][y];
      int n = n0 + wn + y * 16 + col;
      float bv = bias[n];
#pragma unroll
      for (int r = 0; r < 4; r++) out[(size_t)(s0r + r) * DM + n] = a[r] + bv;
    }
  }
}

// =================================================================
// Split-KV flash attention, fixed-max (m=0) softmax — EXACT R10 body
// (verified 55us @ 187.8us total). 4-wave (256-thread) blocks, 128
// q-rows per block; each wave owns 32 rows (64 VGPR state). 16KB
// single-buffer LDS K/V staging; 2 barriers/step. Grid 1280 = 5
// blocks/CU, entire grid co-resident. Head->XCD affinity: heads h,
// h+8 pinned to XCD h -> K/V L2-resident (FETCH ~12MB). Split-KV:
// 1-way (qb<8), 2-way (qb 8..19), 4-way (qb 20..31) at row
// boundaries 1024/2560.
// =================================================================
__global__ void __launch_bounds__(256, 4) attn(const unsigned short* __restrict__ Q,
                                               const unsigned short* __restrict__ K,
                                               const unsigned short* __restrict__ Vt,
                                               unsigned short* __restrict__ slabA,
                                               unsigned short* __restrict__ slab1,
                                               unsigned short* __restrict__ slab2,
                                               unsigned short* __restrict__ slab3,
                                               float* __restrict__ l0_g,
                                               float* __restrict__ l1_g,
                                               float* __restrict__ l2_g,
                                               float* __restrict__ l3_g) {
  __shared__ unsigned short kbuf[64 * 64];       // [kv][d], swizzled chunks
  __shared__ unsigned short vbuf[64 * 64];       // [d][kv], swizzled chunks

  int bid = blockIdx.x;
  int xcd = bid & 7;                             // dispatch round-robin heuristic
  int kk = bid >> 3;                             // 0..159 within this XCD
  int h = xcd + ((kk >= 80) ? 8 : 0);            // heads h, h+8 pinned to XCD h
  int cidx = (kk >= 80) ? (kk - 80) : kk;        // 0..79
  int j = 79 - cidx;                             // longest chunks first
  int qb, c0, nst, p;
  if (j < 8) {
    qb = j; c0 = 0; nst = 2 * qb + 2; p = 0;
  } else if (j < 32) {
    int u = j - 8;
    qb = 8 + (u >> 1);
    int half = u & 1;
    int nh = qb + 1;                             // ntot = 2qb+2, even split
    p = half;
    c0 = half ? nh : 0;
    nst = nh;
  } else {
    int u = j - 32;
    qb = 20 + (u >> 2);
    int qt = u & 3;
    int ntot = 2 * qb + 2;
    int base = ntot >> 2, rem = ntot & 3;
    c0 = qt * base + (qt < rem ? qt : rem);
    nst = base + (qt < rem ? 1 : 0);
    p = qt;
  }
  bool single = (j < 8);
  int q0blk = qb * 128;
  int t = threadIdx.x, w = t >> 6, lane = t & 63;
  int col = lane & 15, quad = lane >> 4;
  int q0 = q0blk + w * 32;                       // wave covers 32 q-rows

  const unsigned short* Qh = Q + (size_t)h * S * HD;
  const unsigned short* Kh = K + (size_t)h * S * HD;
  const unsigned short* Vh = Vt + (size_t)h * HD * S;

  // Q^T B-fragments for the 2 q-groups: lane holds Q[q16+col][k-range]
  bf8 qf[2][2];
#pragma unroll
  for (int g = 0; g < 2; g++) {
    qf[g][0] = *(const bf8*)(Qh + (q0 + g * 16 + col) * HD + quad * 8);
    qf[g][1] = *(const bf8*)(Qh + (q0 + g * 16 + col) * HD + 32 + quad * 8);
  }

  f4 o[2][4];
#pragma unroll
  for (int g = 0; g < 2; g++)
#pragma unroll
    for (int dt = 0; dt < 4; dt++) o[g][dt] = (f4){0.f, 0.f, 0.f, 0.f};
  float lsum[2] = {0.f, 0.f};                    // per-lane partial; reduced at end

  int srow = lane >> 3;          // 0..7 within an 8-row staging group
  int sphys = lane & 7;

  for (int s_ = 0; s_ < nst; s_++) {
    int kv0 = (c0 + s_) * 64;
    __syncthreads();             // WAR: prev-step k/v consumers done
#pragma unroll
    for (int pp = 0; pp < 2; pp++) {
      int jj = 2 * w + pp;                     // 8 groups across 4 waves
      int row = jj * 8 + srow;                 // 0..63
      int lch = sphys ^ (row & 7);
      gld_lds(Kh + (size_t)(kv0 + row) * HD + lch * 8, kbuf + jj * 512);
      gld_lds(Vh + (size_t)row * S + kv0 + lch * 8, vbuf + jj * 512);
    }
    __syncthreads();             // staged data visible

    // ---- scores S^T[kv][q] from LDS K; K-frags shared by both q-groups ----
    f4 st[2][4];
#pragma unroll
    for (int tt = 0; tt < 4; tt++) {
      int kr = tt * 16 + col;
      int sw = col & 7;
      bf8 ka = *(const bf8*)(kbuf + kr * 64 + (quad ^ sw) * 8);
      bf8 kb = *(const bf8*)(kbuf + kr * 64 + ((quad + 4) ^ sw) * 8);
#pragma unroll
      for (int g = 0; g < 2; g++) {
        f4 z = {0.f, 0.f, 0.f, 0.f};
        z = MFMA(ka, qf[g][0], z, 0, 0, 0);
        z = MFMA(kb, qf[g][1], z, 0, 0, 0);
        st[g][tt] = z;
      }
    }

#pragma unroll
    for (int g = 0; g < 2; g++) {
      int q16 = q0 + g * 16;
      if (kv0 + 63 > q16) {                    // diagonal / masked tiles
        int q = q16 + col;
#pragma unroll
        for (int tt = 0; tt < 4; tt++)
#pragma unroll
          for (int rr = 0; rr < 4; rr++) {
            int kv = kv0 + tt * 16 + quad * 4 + rr;
            st[g][tt][rr] = (kv <= q) ? st[g][tt][rr] : -1e30f;
          }
      }
    }

    // ---- fixed-max softmax + in-register P transpose ----
    // st layout: lane(quad,col) holds P[q=col][kv=16tt+4quad+rr].
    // PV A-fragment needs:     lane(quad,col) holds P[q=col][kv=8quad+j].
    // cvt_pk pairs -> permlane32_swap -> permlane16_swap.
    bf8 pf[2][2];
#pragma unroll
    for (int g = 0; g < 2; g++) {
      float pv[4][4];
#pragma unroll
      for (int tt = 0; tt < 4; tt++) {
#pragma unroll
        for (int rr = 0; rr < 4; rr++) pv[tt][rr] = __builtin_amdgcn_exp2f(st[g][tt][rr]);
        lsum[g] += (pv[tt][0] + pv[tt][1]) + (pv[tt][2] + pv[tt][3]);
      }
#pragma unroll
      for (int f = 0; f < 2; f++) {
        unsigned int a0, a1, b0, b1;
        asm("v_cvt_pk_bf16_f32 %0, %1, %2" : "=v"(a0) : "v"(pv[2 * f][0]),     "v"(pv[2 * f][1]));
        asm("v_cvt_pk_bf16_f32 %0, %1, %2" : "=v"(a1) : "v"(pv[2 * f][2]),     "v"(pv[2 * f][3]));
        asm("v_cvt_pk_bf16_f32 %0, %1, %2" : "=v"(b0) : "v"(pv[2 * f + 1][0]), "v"(pv[2 * f + 1][1]));
        asm("v_cvt_pk_bf16_f32 %0, %1, %2" : "=v"(b1) : "v"(pv[2 * f + 1][2]), "v"(pv[2 * f + 1][3]));
        asm("v_permlane32_swap_b32 %0, %1" : "+v"(a0), "+v"(b0));
        asm("v_permlane32_swap_b32 %0, %1" : "+v"(a1), "+v"(b1));
        asm("v_permlane16_swap_b32 %0, %1" : "+v"(a0), "+v"(b0));
        asm("v_permlane16_swap_b32 %0, %1" : "+v"(a1), "+v"(b1));
        u4 pk;
        pk.x = a0; pk.y = a1; pk.z = b0; pk.w = b1;
        pf[g][f] = __builtin_bit_cast(bf8, pk);
      }
    }

    // ---- PV: V-frags shared by both q-groups ----
#pragma unroll
    for (int dt = 0; dt < 4; dt++) {
      int vr = dt * 16 + col;
      int sw = col & 7;
      bf8 v0 = *(const bf8*)(vbuf + vr * 64 + (quad ^ sw) * 8);
      bf8 v1 = *(const bf8*)(vbuf + vr * 64 + ((quad + 4) ^ sw) * 8);
#pragma unroll
      for (int g = 0; g < 2; g++) {
        o[g][dt] = MFMA(pf[g][0], v0, o[g][dt], 0, 0, 0);
        o[g][dt] = MFMA(pf[g][1], v1, o[g][dt], 0, 0, 0);
      }
    }
  }

  // ---- epilogue per q-group: cross-lane l reduce (q = col) ----
#pragma unroll
  for (int g = 0; g < 2; g++) {
    float ls = lsum[g];
    ls += __shfl_xor(ls, 16);
    ls += __shfl_xor(ls, 32);
    int q16 = q0 + g * 16;
    if (single) {
      float inv = 1.0f / ls;
      float ir[4];
#pragma unroll
      for (int rr = 0; rr < 4; rr++) ir[rr] = __shfl(inv, quad * 4 + rr);
#pragma unroll
      for (int dt = 0; dt < 4; dt++)
#pragma unroll
        for (int rr = 0; rr < 4; rr++) {
          int row = q16 + quad * 4 + rr;
          slabA[(size_t)row * DM + h * HD + dt * 16 + col] = f2b(o[g][dt][rr] * ir[rr]);
        }
    } else {
      unsigned short* slab; int rowbase; float* lg;
      if (p == 0)      { slab = slabA; rowbase = q16;        lg = l0_g; }
      else if (p == 1) { slab = slab1; rowbase = q16 - 1024; lg = l1_g; }
      else if (p == 2) { slab = slab2; rowbase = q16 - 2560; lg = l2_g; }
      else             { slab = slab3; rowbase = q16 - 2560; lg = l3_g; }
      if (quad == 0) lg[h * S + q16 + col] = ls;
#pragma unroll
      for (int dt = 0; dt < 4; dt++)
#pragma unroll
        for (int rr = 0; rr < 4; rr++) {
          int row = rowbase + quad * 4 + rr;
          slab[(size_t)row * DM + h * HD + dt * 16 + col] = f2b(o[g][dt][rr]);
        }
    }
  }
}

// ------------- combine bf16 partials -> normalized ctx rows 1024+ -------------
// rows 1024..2559: 2 partials (ctx + slab1); rows 2560..4095: 4 partials.
__global__ void combine(unsigned short* __restrict__ Ctx,
                        const unsigned short* __restrict__ slab1,
                        const unsigned short* __restrict__ slab2,
                        const unsigned short* __restrict__ slab3,
                        const float* __restrict__ l0_g,
                        const float* __restrict__ l1_g,
                        const float* __restrict__ l2_g,
                        const float* __restrict__ l3_g) {
  int row = 1024 + blockIdx.x;
  int cc = threadIdx.x * 4;
  int h = cc >> 6;
  s4 a = *(const s4*)(Ctx + (size_t)row * DM + cc);
  s4 b = *(const s4*)(slab1 + (size_t)(row - 1024) * DM + cc);
  float acc0 = b2f((unsigned short)a.x) + b2f((unsigned short)b.x);
  float acc1 = b2f((unsigned short)a.y) + b2f((unsigned short)b.y);
  float acc2 = b2f((unsigned short)a.z) + b2f((unsigned short)b.z);
  float acc3 = b2f((unsigned short)a.w) + b2f((unsigned short)b.w);
  float l = l0_g[h * S + row] + l1_g[h * S + row];
  if (row >= 2560) {
    s4 c = *(const s4*)(slab2 + (size_t)(row - 2560) * DM + cc);
    s4 d = *(const s4*)(slab3 + (size_t)(row - 2560) * DM + cc);
    acc0 += b2f((unsigned short)c.x) + b2f((unsigned short)d.x);
    acc1 += b2f((unsigned short)c.y) + b2f((unsigned short)d.y);
    acc2 += b2f((unsigned short)c.z) + b2f((unsigned short)d.z);
    acc3 += b2f((unsigned short)c.w) + b2f((unsigned short)d.w);
    l += l2_g[h * S + row] + l3_g[h * S + row];
  }
  float inv = 1.0f / l;
  s4 o;
  o.x = (short)f2b(acc0 * inv);
  o.y = (short)f2b(acc1 * inv);
  o.z = (short)f2b(acc2 * inv);
  o.w = (short)f2b(acc3 * inv);
  *(s4*)(Ctx + (size_t)row * DM + cc) = o;
}

extern "C" void kernel_launch(void* const* d_in, const int* in_sizes, int n_in,
                              void* d_out, int out_size, void* d_ws, size_t ws_size,
                              hipStream_t stream) {
  const float* x     = (const float*)d_in[0];
  const float* w_qkv = (const float*)d_in[1];
  const float* b_qkv = (const float*)d_in[2];
  const float* w_out = (const float*)d_in[3];
  const float* b_out = (const float*)d_in[4];
  float* out = (float*)d_out;

  char* ws = (char*)d_ws;
  unsigned short* xb    = (unsigned short*)(ws);                        //  8 MB (dead after gemm_qkv)
  unsigned short* wqkvT = (unsigned short*)(ws + (size_t)8  * 1048576); //  6 MB (dead after gemm_qkv)
  unsigned short* woutT = (unsigned short*)(ws + (size_t)14 * 1048576); //  2 MB (live till gemm_out)
  unsigned short* Qb    = (unsigned short*)(ws + (size_t)16 * 1048576); //  8 MB
  unsigned short* Kb    = (unsigned short*)(ws + (size_t)24 * 1048576); //  8 MB
  unsigned short* Vtb   = (unsigned short*)(ws + (size_t)32 * 1048576); //  8 MB
  unsigned short* ctx   = (unsigned short*)(ws + (size_t)40 * 1048576); //  8 MB (= slabA)

  // dead-region reuse (gemm_qkv has consumed xb/wqkvT before attn runs):
  // xb region (8MB):    slab1 (rows 1024+, 6MB) + l0..l3 (4 x 256KB)
  // wqkvT region (6MB): slab2 (rows 2560+, 3MB) + slab3 (3MB)
  unsigned short* slab1 = xb;
  float* l0_g = (float*)(ws + (size_t)6 * 1048576);
  float* l1_g = (float*)(ws + (size_t)6 * 1048576 + 256 * 1024);
  float* l2_g = (float*)(ws + (size_t)6 * 1048576 + 512 * 1024);
  float* l3_g = (float*)(ws + (size_t)6 * 1048576 + 768 * 1024);
  unsigned short* slab2 = wqkvT;
  unsigned short* slab3 = (unsigned short*)(ws + (size_t)11 * 1048576);

  prep<<<5120, 256, 0, stream>>>(x, w_qkv, w_out, xb, wqkvT, woutT);
  gemm_qkv<<<32 * 24, 256, 0, stream>>>(xb, wqkvT, b_qkv, Qb, Kb, Vtb);
  attn<<<1280, 256, 0, stream>>>(Qb, Kb, Vtb, ctx, slab1, slab2, slab3,
                                 l0_g, l1_g, l2_g, l3_g);
  combine<<<3072, 256, 0, stream>>>(ctx, slab1, slab2, slab3, l0_g, l1_g, l2_g, l3_g);
  gemm_out<<<64 * 8, 256, 0, stream>>>(ctx, woutT, b_out, out);
}